// Round 10
// baseline (529.145 us; speedup 1.0000x reference)
//
#include <hip/hip_runtime.h>
#include <hip/hip_fp16.h>

#define NEG_SLOPE 0.2f

constexpr int NN = 50000;   // nodes
constexpr int EE = 800000;  // edges (before self loops)

static inline int cdiv(int a, int b) { return (a + b - 1) / b; }

typedef _Float16 h2 __attribute__((ext_vector_type(2)));

#if __has_builtin(__builtin_amdgcn_fdot2)
static __device__ inline float fdot2f(h2 a, h2 b, float c) {
    return __builtin_amdgcn_fdot2(a, b, c, false);
}
#else
static __device__ inline float fdot2f(h2 a, h2 b, float c) {
    return c + (float)a.x * (float)b.x + (float)a.y * (float)b.y;
}
#endif

static __device__ inline h2 bch2(unsigned u) { return __builtin_bit_cast(h2, u); }

// 32-byte edge record: fp16 edge attrs + src id (always within one 64B line)
struct __align__(16) ERec {
    __half ea[8];   // 16 B
    int src;        // 4 B
    int pad[3];     // 12 B
};

// ================= CSR build =================
__global__ void hist_kernel(const int* __restrict__ dst, int* __restrict__ rowcnt, int E) {
    int t = blockIdx.x * blockDim.x + threadIdx.x;
    if (t < E) atomicAdd(&rowcnt[dst[t]], 1);
}

// per-block inclusive scan of (cnt+1) [+1 = self loop]
__global__ void scan1_kernel(const int* __restrict__ cnt, int* __restrict__ local,
                             int* __restrict__ blocksum, int n) {
    __shared__ int s[256];
    int t = threadIdx.x, g = blockIdx.x * 256 + t;
    int v = (g < n) ? cnt[g] + 1 : 0;
    s[t] = v; __syncthreads();
    for (int off = 1; off < 256; off <<= 1) {
        int tv = (t >= off) ? s[t - off] : 0; __syncthreads();
        s[t] += tv; __syncthreads();
    }
    if (g < n) local[g] = s[t];
    if (t == 255) blocksum[blockIdx.x] = s[255];
}

__global__ void scan2_kernel(int* __restrict__ blocksum, int nb) {
    __shared__ int s[256];
    int t = threadIdx.x;
    int v = (t < nb) ? blocksum[t] : 0;
    s[t] = v; __syncthreads();
    for (int off = 1; off < 256; off <<= 1) {
        int tv = (t >= off) ? s[t - off] : 0; __syncthreads();
        s[t] += tv; __syncthreads();
    }
    if (t < nb) blocksum[t] = s[t] - v;   // exclusive
}

// rowptr, cursor (past reserved self-loop front slot), self-loop src into record
__global__ void scan3_kernel(const int* __restrict__ local, const int* __restrict__ blocksum,
                             const int* __restrict__ cnt, int* __restrict__ rowptr,
                             int* __restrict__ cursor, ERec* __restrict__ csr, int n) {
    int g = blockIdx.x * 256 + threadIdx.x;
    if (g >= n) return;
    int incl = local[g] + blocksum[blockIdx.x];
    rowptr[g + 1] = incl;
    int beg = incl - (cnt[g] + 1);
    cursor[g] = beg + 1;          // slot `beg` reserved for the self loop
    csr[beg].src = g;             // self-loop source
    if (g == 0) rowptr[0] = 0;
}

// scatter edges into CSR records (fp16 edge attrs, CSR order; one 32B record)
__global__ void scatter_kernel(const int* __restrict__ src, const int* __restrict__ dst,
                               const float* __restrict__ eattr,
                               int* __restrict__ cursor, ERec* __restrict__ csr, int E) {
    int t = blockIdx.x * blockDim.x + threadIdx.x;
    if (t >= E) return;
    int d = dst[t];
    int pos = atomicAdd(&cursor[d], 1);
    const float4* ea4 = (const float4*)(eattr + (size_t)t * 8);
    float4 a = ea4[0], b = ea4[1];
    __half2 h0 = __floats2half2_rn(a.x, a.y);
    __half2 h1 = __floats2half2_rn(a.z, a.w);
    __half2 h2v = __floats2half2_rn(b.x, b.y);
    __half2 h3 = __floats2half2_rn(b.z, b.w);
    uint4 u;
    u.x = *(unsigned*)&h0; u.y = *(unsigned*)&h1;
    u.z = *(unsigned*)&h2v; u.w = *(unsigned*)&h3;
    ERec* r = &csr[pos];
    *(uint4*)r->ea = u;
    uint4 tail; tail.x = (unsigned)src[t]; tail.y = 0; tail.z = 0; tail.w = 0;
    *(uint4*)(&r->src) = tail;   // full 32 B record written
}

// fill each row's front slot with the mean of its (original) edge attrs
__global__ __launch_bounds__(256) void loop_sea_kernel(const int* __restrict__ rowptr,
                                                       ERec* __restrict__ csr, int n) {
    int wave = (blockIdx.x * 256 + threadIdx.x) >> 6;
    int lane = threadIdx.x & 63;
    if (wave >= n) return;
    int beg = rowptr[wave], end = rowptr[wave + 1];
    int k = lane & 7, j0 = lane >> 3;       // 8 edges in parallel
    float s = 0.f;
    for (int j = beg + 1 + j0; j < end; j += 8)
        s += __half2float(csr[j].ea[k]);
    s += __shfl_xor(s, 8); s += __shfl_xor(s, 16); s += __shfl_xor(s, 32);
    int cnt = end - beg - 1;
    if (lane < 8) csr[beg].ea[lane] = __float2half(s / fmaxf((float)cnt, 1.f));
}

// ================= node linear: xl = x@Wl+bl, xr = x@Wr+br (fp16 out) =========
template <int K, int CT>
__global__ __launch_bounds__(256) void node_linear_kernel(
    const float* __restrict__ x,
    const float* __restrict__ Wl, const float* __restrict__ bl,
    const float* __restrict__ Wr, const float* __restrict__ br,
    __half* __restrict__ xl, __half* __restrict__ xr, int n) {
    constexpr int NPB = 256 / CT;
    __shared__ float Wls[K * CT];
    __shared__ float Wrs[K * CT];
    __shared__ float xs[NPB * K];
    int tid = threadIdx.y * CT + threadIdx.x;
    for (int i = tid; i < K * CT; i += 256) { Wls[i] = Wl[i]; Wrs[i] = Wr[i]; }
    int node0 = blockIdx.x * NPB;
    for (int i = tid; i < NPB * K; i += 256) {
        int nd = node0 + i / K;
        xs[i] = (nd < n) ? x[(size_t)node0 * K + i] : 0.f;
    }
    __syncthreads();
    int node = node0 + threadIdx.y;
    if (node >= n) return;
    int c = threadIdx.x;
    float aL = bl[c], aR = br[c];
    const float* xrow = &xs[threadIdx.y * K];
    for (int k = 0; k < K; ++k) {
        float xv = xrow[k];
        aL = fmaf(xv, Wls[k * CT + c], aL);
        aR = fmaf(xv, Wrs[k * CT + c], aR);
    }
    xl[(size_t)node * CT + c] = __float2half(aL);
    xr[(size_t)node * CT + c] = __float2half(aR);
}

// ================= CSR aggregation, CT=128 (layer 2) =================
// One wave per node; 2 edge-chains per wave (32 lanes each, 4 ch/lane).
// Per-64-edge batch: wave stages srcs into its private LDS slice, so the
// per-edge xl gather no longer waits on a global src load (2-level -> 1-level).
template <bool RELU, bool RES>
__global__ __launch_bounds__(256) void agg128_kernel(
    const int* __restrict__ rowptr, const ERec* __restrict__ csr,
    const __half* __restrict__ xl, const __half* __restrict__ xr,
    const float* __restrict__ We,   // [8,128]
    const float* __restrict__ att,  // flat [128]
    const float* __restrict__ bias, // [128]
    const float* __restrict__ hres, // [N,32] if RES
    const float* __restrict__ Rw,   // [32,128] if RES
    float* __restrict__ out, int n) {
    __shared__ float Rws[RES ? 32 * 128 : 1];
    __shared__ int ssrc[4][64];     // per-wave src slice (wave-synchronous, no barrier)
    int tid = threadIdx.x;
    if (RES) {
        for (int i = tid; i < 32 * 128; i += 256) Rws[i] = Rw[i];
        __syncthreads();
    }
    int node = (blockIdx.x * 256 + tid) >> 6;
    int wv = tid >> 6;
    int lane = tid & 63;
    if (node >= n) return;
    int sub = lane >> 5, cl = lane & 31;
    int c0 = 4 * cl;
    h2 wch[4][4];
    float attc[4];
#pragma unroll
    for (int c = 0; c < 4; ++c) {
        attc[c] = att[c0 + c];
#pragma unroll
        for (int k = 0; k < 4; ++k)
            wch[c][k] = h2{(_Float16)We[(2 * k) * 128 + c0 + c],
                           (_Float16)We[(2 * k + 1) * 128 + c0 + c]};
    }
    int beg = rowptr[node], end = rowptr[node + 1];
    int cnt = end - beg;
    uint2 xru = *(const uint2*)&xr[(size_t)node * 128 + c0];
    h2 xr01 = bch2(xru.x), xr23 = bch2(xru.y);
    float xrc[4] = {(float)xr01.x, (float)xr01.y, (float)xr23.x, (float)xr23.y};
    float num[4] = {0.f, 0.f, 0.f, 0.f};
    float den = 0.f;

    for (int base = 0; base < cnt; base += 64) {
        int nb = min(64, cnt - base);
        int g0 = beg + base;
        if (lane < nb) ssrc[wv][lane] = csr[g0 + lane].src;   // also warms L1 with records
        int i = sub;
        uint4 uA, uB; uint2 xA, xB;
        if (i < nb) {
            uA = *(const uint4*)csr[g0 + i].ea;
            xA = *(const uint2*)&xl[(size_t)ssrc[wv][i] * 128 + c0];
        }
        if (i + 2 < nb) {
            uB = *(const uint4*)csr[g0 + i + 2].ea;
            xB = *(const uint2*)&xl[(size_t)ssrc[wv][i + 2] * 128 + c0];
        }
        while (i < nb) {
            int ip = i + 4;
            uint4 uC; uint2 xC;
            if (ip < nb) {                     // prefetch 2 ahead (src from LDS)
                uC = *(const uint4*)csr[g0 + ip].ea;
                xC = *(const uint2*)&xl[(size_t)ssrc[wv][ip] * 128 + c0];
            }
            h2 e0 = bch2(uA.x), e1 = bch2(uA.y), e2 = bch2(uA.z), e3 = bch2(uA.w);
            h2 xl01 = bch2(xA.x), xl23 = bch2(xA.y);
            float xls[4] = {(float)xl01.x, (float)xl01.y, (float)xl23.x, (float)xl23.y};
            float p = 0.f;
#pragma unroll
            for (int c = 0; c < 4; ++c) {
                float m = xls[c] + xrc[c];
                m = fdot2f(e0, wch[c][0], m); m = fdot2f(e1, wch[c][1], m);
                m = fdot2f(e2, wch[c][2], m); m = fdot2f(e3, wch[c][3], m);
                float sv = fmaxf(m, 0.f) + NEG_SLOPE * fminf(m, 0.f);
                p = fmaf(sv, attc[c], p);
            }
            p += __shfl_xor(p, 1); p += __shfl_xor(p, 2); p += __shfl_xor(p, 4); // 8-lane head
            float wgt = __expf(p);
#pragma unroll
            for (int c = 0; c < 4; ++c) num[c] = fmaf(wgt, xls[c], num[c]);
            den += wgt;
            i += 2;
            uA = uB; xA = xB;
            uB = uC; xB = xC;
        }
    }
    // combine the two 32-lane chains
#pragma unroll
    for (int c = 0; c < 4; ++c) num[c] += __shfl_xor(num[c], 32);
    den += __shfl_xor(den, 32);
    if (sub == 0) {
        float inv = 1.f / den;
        float v[4];
#pragma unroll
        for (int c = 0; c < 4; ++c) v[c] = num[c] * inv + bias[c0 + c];
        if (RES) {
            float hr = hres[(size_t)node * 32 + cl];
#pragma unroll
            for (int k = 0; k < 32; ++k) {
                float hv = __shfl(hr, k, 32);
                float4 rw = *(const float4*)&Rws[k * 128 + c0];
                v[0] = fmaf(hv, rw.x, v[0]); v[1] = fmaf(hv, rw.y, v[1]);
                v[2] = fmaf(hv, rw.z, v[2]); v[3] = fmaf(hv, rw.w, v[3]);
            }
        }
        if (RELU) {
#pragma unroll
            for (int c = 0; c < 4; ++c) v[c] = fmaxf(v[c], 0.f);
        }
        float4 o; o.x = v[0]; o.y = v[1]; o.z = v[2]; o.w = v[3];
        *(float4*)&out[(size_t)node * 128 + c0] = o;
    }
}

// ================= CSR aggregation, CT=32 (layers 1, 3) =================
// One wave per node; 4 edge-chains (16 lanes, 2 ch/lane); LDS src slice +
// 2-stage pipeline. HC = channels per head.
template <int HC, bool RELU>
__global__ __launch_bounds__(256) void agg32_kernel(
    const int* __restrict__ rowptr, const ERec* __restrict__ csr,
    const __half* __restrict__ xl, const __half* __restrict__ xr,
    const float* __restrict__ We,   // [8,32]
    const float* __restrict__ att,  // flat [32]
    const float* __restrict__ bias, // [32]
    float* __restrict__ out, int n) {
    __shared__ int ssrc[4][64];
    int tid = threadIdx.x;
    int node = (blockIdx.x * 256 + tid) >> 6;
    int wv = tid >> 6;
    int lane = tid & 63;
    if (node >= n) return;
    int g = lane >> 4, q = lane & 15;
    int c0 = 2 * q;
    h2 wc0[4], wc1[4];
#pragma unroll
    for (int k = 0; k < 4; ++k) {
        wc0[k] = h2{(_Float16)We[(2 * k) * 32 + c0], (_Float16)We[(2 * k + 1) * 32 + c0]};
        wc1[k] = h2{(_Float16)We[(2 * k) * 32 + c0 + 1], (_Float16)We[(2 * k + 1) * 32 + c0 + 1]};
    }
    float att0 = att[c0], att1 = att[c0 + 1];
    int beg = rowptr[node], end = rowptr[node + 1];
    int cnt = end - beg;
    h2 xrh = bch2(*(const unsigned*)&xr[(size_t)node * 32 + c0]);
    float xrc0 = (float)xrh.x, xrc1 = (float)xrh.y;
    float num0 = 0.f, num1 = 0.f, den = 0.f;

    for (int base = 0; base < cnt; base += 64) {
        int nb = min(64, cnt - base);
        int g0 = beg + base;
        if (lane < nb) ssrc[wv][lane] = csr[g0 + lane].src;
        int i = g;
        uint4 uA, uB; unsigned xA, xB;
        if (i < nb) {
            uA = *(const uint4*)csr[g0 + i].ea;
            xA = *(const unsigned*)&xl[(size_t)ssrc[wv][i] * 32 + c0];
        }
        if (i + 4 < nb) {
            uB = *(const uint4*)csr[g0 + i + 4].ea;
            xB = *(const unsigned*)&xl[(size_t)ssrc[wv][i + 4] * 32 + c0];
        }
        while (i < nb) {
            int ip = i + 8;
            uint4 uC; unsigned xC;
            if (ip < nb) {                     // prefetch 2 ahead (src from LDS)
                uC = *(const uint4*)csr[g0 + ip].ea;
                xC = *(const unsigned*)&xl[(size_t)ssrc[wv][ip] * 32 + c0];
            }
            h2 e0 = bch2(uA.x), e1 = bch2(uA.y), e2 = bch2(uA.z), e3 = bch2(uA.w);
            h2 xlh = bch2(xA);
            float xls0 = (float)xlh.x, xls1 = (float)xlh.y;
            float m0 = xls0 + xrc0, m1 = xls1 + xrc1;
            m0 = fdot2f(e0, wc0[0], m0); m0 = fdot2f(e1, wc0[1], m0);
            m0 = fdot2f(e2, wc0[2], m0); m0 = fdot2f(e3, wc0[3], m0);
            m1 = fdot2f(e0, wc1[0], m1); m1 = fdot2f(e1, wc1[1], m1);
            m1 = fdot2f(e2, wc1[2], m1); m1 = fdot2f(e3, wc1[3], m1);
            float s0 = fmaxf(m0, 0.f) + NEG_SLOPE * fminf(m0, 0.f);
            float s1 = fmaxf(m1, 0.f) + NEG_SLOPE * fminf(m1, 0.f);
            float p = fmaf(s0, att0, s1 * att1);
#pragma unroll
            for (int off = HC / 4; off > 0; off >>= 1) p += __shfl_xor(p, off); // head group
            float wgt = __expf(p);
            num0 = fmaf(wgt, xls0, num0);
            num1 = fmaf(wgt, xls1, num1);
            den += wgt;
            i += 4;
            uA = uB; xA = xB;
            uB = uC; xB = xC;
        }
    }
    // combine the four 16-lane chains
    num0 += __shfl_xor(num0, 16); num0 += __shfl_xor(num0, 32);
    num1 += __shfl_xor(num1, 16); num1 += __shfl_xor(num1, 32);
    den  += __shfl_xor(den, 16);  den  += __shfl_xor(den, 32);
    if (g == 0) {
        float inv = 1.f / den;
        float v0 = num0 * inv + bias[c0];
        float v1 = num1 * inv + bias[c0 + 1];
        if (RELU) { v0 = fmaxf(v0, 0.f); v1 = fmaxf(v1, 0.f); }
        float2 o; o.x = v0; o.y = v1;
        *(float2*)&out[(size_t)node * 32 + c0] = o;
    }
}

extern "C" void kernel_launch(void* const* d_in, const int* in_sizes, int n_in,
                              void* d_out, int out_size, void* d_ws, size_t ws_size,
                              hipStream_t stream) {
    const float* x    = (const float*)d_in[0];
    const int* ei     = (const int*)d_in[1];
    const float* eatt = (const float*)d_in[2];
    const float* Wl1 = (const float*)d_in[3],  *bl1 = (const float*)d_in[4];
    const float* Wr1 = (const float*)d_in[5],  *br1 = (const float*)d_in[6];
    const float* We1 = (const float*)d_in[7],  *att1 = (const float*)d_in[8];
    const float* b1  = (const float*)d_in[9];
    const float* Wl2 = (const float*)d_in[10], *bl2 = (const float*)d_in[11];
    const float* Wr2 = (const float*)d_in[12], *br2 = (const float*)d_in[13];
    const float* We2 = (const float*)d_in[14], *att2 = (const float*)d_in[15];
    const float* b2  = (const float*)d_in[16], *Rw2 = (const float*)d_in[17];
    const float* Wl3 = (const float*)d_in[18], *bl3 = (const float*)d_in[19];
    const float* Wr3 = (const float*)d_in[20], *br3 = (const float*)d_in[21];
    const float* We3 = (const float*)d_in[22], *att3 = (const float*)d_in[23];
    const float* b3  = (const float*)d_in[24];

    const int* srcp = ei;
    const int* dstp = ei + EE;

    // ---- workspace layout (~84 MB) ----
    char* w = (char*)d_ws;
    size_t off = 0;
    auto alloc = [&](size_t bytes) { char* p = w + off; off += (bytes + 255) & ~size_t(255); return p; };
    int*    rowcnt   = (int*)alloc((size_t)NN * 4);
    int*    rowptr   = (int*)alloc((size_t)(NN + 1) * 4);
    int*    cursor   = (int*)alloc((size_t)NN * 4);
    int*    blocksum = (int*)alloc(256 * 4);
    int*    local    = (int*)alloc((size_t)NN * 4);
    ERec*   csr      = (ERec*)alloc((size_t)(EE + NN) * sizeof(ERec));
    __half* xlbuf    = (__half*)alloc((size_t)NN * 128 * 2);
    __half* xrbuf    = (__half*)alloc((size_t)NN * 128 * 2);
    float*  hA       = (float*)alloc((size_t)NN * 32 * 4);
    float*  hB       = (float*)alloc((size_t)NN * 128 * 4);

    int nb = cdiv(NN, 256);

    // ---- CSR build (self-loop in front slot of each row) ----
    hipMemsetAsync(rowcnt, 0, (size_t)NN * 4, stream);
    hist_kernel<<<cdiv(EE, 256), 256, 0, stream>>>(dstp, rowcnt, EE);
    scan1_kernel<<<nb, 256, 0, stream>>>(rowcnt, local, blocksum, NN);
    scan2_kernel<<<1, 256, 0, stream>>>(blocksum, nb);
    scan3_kernel<<<nb, 256, 0, stream>>>(local, blocksum, rowcnt, rowptr, cursor, csr, NN);
    scatter_kernel<<<cdiv(EE, 256), 256, 0, stream>>>(
        srcp, dstp, eatt, cursor, csr, EE);
    loop_sea_kernel<<<cdiv(NN, 4), 256, 0, stream>>>(rowptr, csr, NN);

    // ---- layer 1: IN=16 -> H=4, C=8 (CT=32) ----
    node_linear_kernel<16, 32><<<cdiv(NN, 8), dim3(32, 8), 0, stream>>>(
        x, Wl1, bl1, Wr1, br1, xlbuf, xrbuf, NN);
    agg32_kernel<8, true><<<cdiv(NN, 4), 256, 0, stream>>>(
        rowptr, csr, xlbuf, xrbuf, We1, att1, b1, hA, NN);

    // ---- layer 2: IN=32 -> H=4, C=32 (CT=128), residual ----
    node_linear_kernel<32, 128><<<cdiv(NN, 2), dim3(128, 2), 0, stream>>>(
        hA, Wl2, bl2, Wr2, br2, xlbuf, xrbuf, NN);
    agg128_kernel<true, true><<<cdiv(NN, 4), 256, 0, stream>>>(
        rowptr, csr, xlbuf, xrbuf, We2, att2, b2, hA, Rw2, hB, NN);

    // ---- layer 3: IN=128 -> H=1, C=32 (CT=32) ----
    node_linear_kernel<128, 32><<<cdiv(NN, 8), dim3(32, 8), 0, stream>>>(
        hB, Wl3, bl3, Wr3, br3, xlbuf, xrbuf, NN);
    agg32_kernel<32, false><<<cdiv(NN, 4), 256, 0, stream>>>(
        rowptr, csr, xlbuf, xrbuf, We3, att3, b3,
        (float*)d_out, NN);
}

// Round 11
// 505.360 us; speedup vs baseline: 1.0471x; 1.0471x over previous
//
#include <hip/hip_runtime.h>
#include <hip/hip_fp16.h>

#define NEG_SLOPE 0.2f

constexpr int NN = 50000;   // nodes
constexpr int EE = 800000;  // edges (before self loops)

static inline int cdiv(int a, int b) { return (a + b - 1) / b; }

typedef _Float16 h2 __attribute__((ext_vector_type(2)));

#if __has_builtin(__builtin_amdgcn_fdot2)
static __device__ inline float fdot2f(h2 a, h2 b, float c) {
    return __builtin_amdgcn_fdot2(a, b, c, false);
}
#else
static __device__ inline float fdot2f(h2 a, h2 b, float c) {
    return c + (float)a.x * (float)b.x + (float)a.y * (float)b.y;
}
#endif

static __device__ inline h2 bch2(unsigned u) { return __builtin_bit_cast(h2, u); }

// 32-byte edge record: fp16 edge attrs + src id (always within one 64B line)
struct __align__(16) ERec {
    __half ea[8];   // 16 B
    int src;        // 4 B
    int pad[3];     // 12 B
};

// ================= CSR build =================
__global__ void hist_kernel(const int* __restrict__ dst, int* __restrict__ rowcnt, int E) {
    int t = blockIdx.x * blockDim.x + threadIdx.x;
    if (t < E) atomicAdd(&rowcnt[dst[t]], 1);
}

// per-block inclusive scan of (cnt+1) [+1 = self loop]
__global__ void scan1_kernel(const int* __restrict__ cnt, int* __restrict__ local,
                             int* __restrict__ blocksum, int n) {
    __shared__ int s[256];
    int t = threadIdx.x, g = blockIdx.x * 256 + t;
    int v = (g < n) ? cnt[g] + 1 : 0;
    s[t] = v; __syncthreads();
    for (int off = 1; off < 256; off <<= 1) {
        int tv = (t >= off) ? s[t - off] : 0; __syncthreads();
        s[t] += tv; __syncthreads();
    }
    if (g < n) local[g] = s[t];
    if (t == 255) blocksum[blockIdx.x] = s[255];
}

__global__ void scan2_kernel(int* __restrict__ blocksum, int nb) {
    __shared__ int s[256];
    int t = threadIdx.x;
    int v = (t < nb) ? blocksum[t] : 0;
    s[t] = v; __syncthreads();
    for (int off = 1; off < 256; off <<= 1) {
        int tv = (t >= off) ? s[t - off] : 0; __syncthreads();
        s[t] += tv; __syncthreads();
    }
    if (t < nb) blocksum[t] = s[t] - v;   // exclusive
}

// rowptr, cursor (past reserved self-loop front slot), self-loop src into record
__global__ void scan3_kernel(const int* __restrict__ local, const int* __restrict__ blocksum,
                             const int* __restrict__ cnt, int* __restrict__ rowptr,
                             int* __restrict__ cursor, ERec* __restrict__ csr, int n) {
    int g = blockIdx.x * 256 + threadIdx.x;
    if (g >= n) return;
    int incl = local[g] + blocksum[blockIdx.x];
    rowptr[g + 1] = incl;
    int beg = incl - (cnt[g] + 1);
    cursor[g] = beg + 1;          // slot `beg` reserved for the self loop
    csr[beg].src = g;             // self-loop source
    if (g == 0) rowptr[0] = 0;
}

// scatter edges into CSR records (fp16 edge attrs, CSR order; one 32B record)
__global__ void scatter_kernel(const int* __restrict__ src, const int* __restrict__ dst,
                               const float* __restrict__ eattr,
                               int* __restrict__ cursor, ERec* __restrict__ csr, int E) {
    int t = blockIdx.x * blockDim.x + threadIdx.x;
    if (t >= E) return;
    int d = dst[t];
    int pos = atomicAdd(&cursor[d], 1);
    const float4* ea4 = (const float4*)(eattr + (size_t)t * 8);
    float4 a = ea4[0], b = ea4[1];
    __half2 h0 = __floats2half2_rn(a.x, a.y);
    __half2 h1 = __floats2half2_rn(a.z, a.w);
    __half2 h2v = __floats2half2_rn(b.x, b.y);
    __half2 h3 = __floats2half2_rn(b.z, b.w);
    uint4 u;
    u.x = *(unsigned*)&h0; u.y = *(unsigned*)&h1;
    u.z = *(unsigned*)&h2v; u.w = *(unsigned*)&h3;
    ERec* r = &csr[pos];
    *(uint4*)r->ea = u;
    uint4 tail; tail.x = (unsigned)src[t]; tail.y = 0; tail.z = 0; tail.w = 0;
    *(uint4*)(&r->src) = tail;   // full 32 B record written
}

// fill each row's front slot with the mean of its (original) edge attrs
__global__ __launch_bounds__(256) void loop_sea_kernel(const int* __restrict__ rowptr,
                                                       ERec* __restrict__ csr, int n) {
    int wave = (blockIdx.x * 256 + threadIdx.x) >> 6;
    int lane = threadIdx.x & 63;
    if (wave >= n) return;
    int beg = rowptr[wave], end = rowptr[wave + 1];
    int k = lane & 7, j0 = lane >> 3;       // 8 edges in parallel
    float s = 0.f;
    for (int j = beg + 1 + j0; j < end; j += 8)
        s += __half2float(csr[j].ea[k]);
    s += __shfl_xor(s, 8); s += __shfl_xor(s, 16); s += __shfl_xor(s, 32);
    int cnt = end - beg - 1;
    if (lane < 8) csr[beg].ea[lane] = __float2half(s / fmaxf((float)cnt, 1.f));
}

// ================= node linear: xl = x@Wl+bl, xr = x@Wr+br (fp16 out) =========
template <int K, int CT>
__global__ __launch_bounds__(256) void node_linear_kernel(
    const float* __restrict__ x,
    const float* __restrict__ Wl, const float* __restrict__ bl,
    const float* __restrict__ Wr, const float* __restrict__ br,
    __half* __restrict__ xl, __half* __restrict__ xr, int n) {
    constexpr int NPB = 256 / CT;
    __shared__ float Wls[K * CT];
    __shared__ float Wrs[K * CT];
    __shared__ float xs[NPB * K];
    int tid = threadIdx.y * CT + threadIdx.x;
    for (int i = tid; i < K * CT; i += 256) { Wls[i] = Wl[i]; Wrs[i] = Wr[i]; }
    int node0 = blockIdx.x * NPB;
    for (int i = tid; i < NPB * K; i += 256) {
        int nd = node0 + i / K;
        xs[i] = (nd < n) ? x[(size_t)node0 * K + i] : 0.f;
    }
    __syncthreads();
    int node = node0 + threadIdx.y;
    if (node >= n) return;
    int c = threadIdx.x;
    float aL = bl[c], aR = br[c];
    const float* xrow = &xs[threadIdx.y * K];
    for (int k = 0; k < K; ++k) {
        float xv = xrow[k];
        aL = fmaf(xv, Wls[k * CT + c], aL);
        aR = fmaf(xv, Wrs[k * CT + c], aR);
    }
    xl[(size_t)node * CT + c] = __float2half(aL);
    xr[(size_t)node * CT + c] = __float2half(aR);
}

// ================= CSR aggregation, CT=128 (layer 2) =================
// One wave per node; 2 edge-chains per wave (32 lanes each, 4 ch/lane);
// one-deep software pipeline on record + xl gathers.  [round-5/9 validated, 106us]
template <bool RELU, bool RES>
__global__ __launch_bounds__(256) void agg128_kernel(
    const int* __restrict__ rowptr, const ERec* __restrict__ csr,
    const __half* __restrict__ xl, const __half* __restrict__ xr,
    const float* __restrict__ We,   // [8,128]
    const float* __restrict__ att,  // flat [128]
    const float* __restrict__ bias, // [128]
    const float* __restrict__ hres, // [N,32] if RES
    const float* __restrict__ Rw,   // [32,128] if RES
    float* __restrict__ out, int n) {
    __shared__ float Rws[RES ? 32 * 128 : 1];
    int tid = threadIdx.x;
    if (RES) {
        for (int i = tid; i < 32 * 128; i += 256) Rws[i] = Rw[i];
        __syncthreads();
    }
    int node = (blockIdx.x * 256 + tid) >> 6;
    int lane = tid & 63;
    if (node >= n) return;
    int sub = lane >> 5, cl = lane & 31;
    int c0 = 4 * cl;
    h2 wch[4][4];
    float attc[4];
#pragma unroll
    for (int c = 0; c < 4; ++c) {
        attc[c] = att[c0 + c];
#pragma unroll
        for (int k = 0; k < 4; ++k)
            wch[c][k] = h2{(_Float16)We[(2 * k) * 128 + c0 + c],
                           (_Float16)We[(2 * k + 1) * 128 + c0 + c]};
    }
    int beg = rowptr[node], end = rowptr[node + 1];
    uint2 xru = *(const uint2*)&xr[(size_t)node * 128 + c0];
    h2 xr01 = bch2(xru.x), xr23 = bch2(xru.y);
    float xrc[4] = {(float)xr01.x, (float)xr01.y, (float)xr23.x, (float)xr23.y};
    float num[4] = {0.f, 0.f, 0.f, 0.f};
    float den = 0.f;

    int j = beg + sub;
    uint4 uA, uB; int sA, sB; uint2 xA, xB;
    if (j < end) {
        uA = *(const uint4*)csr[j].ea; sA = csr[j].src;
        xA = *(const uint2*)&xl[(size_t)sA * 128 + c0];
    }
    if (j + 2 < end) {
        uB = *(const uint4*)csr[j + 2].ea; sB = csr[j + 2].src;
        xB = *(const uint2*)&xl[(size_t)sB * 128 + c0];
    }
    while (j < end) {
        int jf = j + 4;
        uint4 uC; int sC; uint2 xC;
        if (jf < end) {                        // prefetch 2 ahead
            uC = *(const uint4*)csr[jf].ea; sC = csr[jf].src;
            xC = *(const uint2*)&xl[(size_t)sC * 128 + c0];
        }
        h2 e0 = bch2(uA.x), e1 = bch2(uA.y), e2 = bch2(uA.z), e3 = bch2(uA.w);
        h2 xl01 = bch2(xA.x), xl23 = bch2(xA.y);
        float xls[4] = {(float)xl01.x, (float)xl01.y, (float)xl23.x, (float)xl23.y};
        float p = 0.f;
#pragma unroll
        for (int c = 0; c < 4; ++c) {
            float m = xls[c] + xrc[c];
            m = fdot2f(e0, wch[c][0], m); m = fdot2f(e1, wch[c][1], m);
            m = fdot2f(e2, wch[c][2], m); m = fdot2f(e3, wch[c][3], m);
            float sv = fmaxf(m, 0.f) + NEG_SLOPE * fminf(m, 0.f);
            p = fmaf(sv, attc[c], p);
        }
        p += __shfl_xor(p, 1); p += __shfl_xor(p, 2); p += __shfl_xor(p, 4); // 8-lane head
        float wgt = __expf(p);
#pragma unroll
        for (int c = 0; c < 4; ++c) num[c] = fmaf(wgt, xls[c], num[c]);
        den += wgt;
        j += 2;
        uA = uB; sA = sB; xA = xB;
        uB = uC; sB = sC; xB = xC;
    }
    // combine the two 32-lane chains
#pragma unroll
    for (int c = 0; c < 4; ++c) num[c] += __shfl_xor(num[c], 32);
    den += __shfl_xor(den, 32);
    if (sub == 0) {
        float inv = 1.f / den;
        float v[4];
#pragma unroll
        for (int c = 0; c < 4; ++c) v[c] = num[c] * inv + bias[c0 + c];
        if (RES) {
            float hr = hres[(size_t)node * 32 + cl];
#pragma unroll
            for (int k = 0; k < 32; ++k) {
                float hv = __shfl(hr, k, 32);
                float4 rw = *(const float4*)&Rws[k * 128 + c0];
                v[0] = fmaf(hv, rw.x, v[0]); v[1] = fmaf(hv, rw.y, v[1]);
                v[2] = fmaf(hv, rw.z, v[2]); v[3] = fmaf(hv, rw.w, v[3]);
            }
        }
        if (RELU) {
#pragma unroll
            for (int c = 0; c < 4; ++c) v[c] = fmaxf(v[c], 0.f);
        }
        float4 o; o.x = v[0]; o.y = v[1]; o.z = v[2]; o.w = v[3];
        *(float4*)&out[(size_t)node * 128 + c0] = o;
    }
}

// ================= CSR aggregation, CT=32 (layers 1, 3) =================
// One 16-lane group per node (4 nodes/wave, 16/block): group walks its row
// serially with a 2-slot pipeline; logit reduce within the group; no
// cross-chain combine; every lane writes its 2 channels. HC = ch per head.
template <int HC, bool RELU>
__global__ __launch_bounds__(256) void agg32_kernel(
    const int* __restrict__ rowptr, const ERec* __restrict__ csr,
    const __half* __restrict__ xl, const __half* __restrict__ xr,
    const float* __restrict__ We,   // [8,32]
    const float* __restrict__ att,  // flat [32]
    const float* __restrict__ bias, // [32]
    float* __restrict__ out, int n) {
    int tid = threadIdx.x;
    int node = (blockIdx.x * 256 + tid) >> 4;   // one 16-lane group per node
    int q = tid & 15;
    if (node >= n) return;
    int c0 = 2 * q;
    h2 wc0[4], wc1[4];
#pragma unroll
    for (int k = 0; k < 4; ++k) {
        wc0[k] = h2{(_Float16)We[(2 * k) * 32 + c0], (_Float16)We[(2 * k + 1) * 32 + c0]};
        wc1[k] = h2{(_Float16)We[(2 * k) * 32 + c0 + 1], (_Float16)We[(2 * k + 1) * 32 + c0 + 1]};
    }
    float att0 = att[c0], att1 = att[c0 + 1];
    int beg = rowptr[node], end = rowptr[node + 1];
    h2 xrh = bch2(*(const unsigned*)&xr[(size_t)node * 32 + c0]);
    float xrc0 = (float)xrh.x, xrc1 = (float)xrh.y;
    float num0 = 0.f, num1 = 0.f, den = 0.f;

    int j = beg;
    uint4 uA, uB; int sA, sB; unsigned xA, xB;
    if (j < end) {
        uA = *(const uint4*)csr[j].ea; sA = csr[j].src;
        xA = *(const unsigned*)&xl[(size_t)sA * 32 + c0];
    }
    if (j + 1 < end) {
        uB = *(const uint4*)csr[j + 1].ea; sB = csr[j + 1].src;
        xB = *(const unsigned*)&xl[(size_t)sB * 32 + c0];
    }
    while (j < end) {
        int jf = j + 2;
        uint4 uC; int sC; unsigned xC;
        if (jf < end) {                        // prefetch 2 ahead
            uC = *(const uint4*)csr[jf].ea; sC = csr[jf].src;
            xC = *(const unsigned*)&xl[(size_t)sC * 32 + c0];
        }
        h2 e0 = bch2(uA.x), e1 = bch2(uA.y), e2 = bch2(uA.z), e3 = bch2(uA.w);
        h2 xlh = bch2(xA);
        float xls0 = (float)xlh.x, xls1 = (float)xlh.y;
        float m0 = xls0 + xrc0, m1 = xls1 + xrc1;
        m0 = fdot2f(e0, wc0[0], m0); m0 = fdot2f(e1, wc0[1], m0);
        m0 = fdot2f(e2, wc0[2], m0); m0 = fdot2f(e3, wc0[3], m0);
        m1 = fdot2f(e0, wc1[0], m1); m1 = fdot2f(e1, wc1[1], m1);
        m1 = fdot2f(e2, wc1[2], m1); m1 = fdot2f(e3, wc1[3], m1);
        float s0 = fmaxf(m0, 0.f) + NEG_SLOPE * fminf(m0, 0.f);
        float s1 = fmaxf(m1, 0.f) + NEG_SLOPE * fminf(m1, 0.f);
        float p = fmaf(s0, att0, s1 * att1);
#pragma unroll
        for (int off = HC / 4; off > 0; off >>= 1) p += __shfl_xor(p, off); // head group
        float wgt = __expf(p);
        num0 = fmaf(wgt, xls0, num0);
        num1 = fmaf(wgt, xls1, num1);
        den += wgt;
        j += 1;
        uA = uB; sA = sB; xA = xB;
        uB = uC; sB = sC; xB = xC;
    }
    float inv = 1.f / den;
    float v0 = num0 * inv + bias[c0];
    float v1 = num1 * inv + bias[c0 + 1];
    if (RELU) { v0 = fmaxf(v0, 0.f); v1 = fmaxf(v1, 0.f); }
    float2 o; o.x = v0; o.y = v1;
    *(float2*)&out[(size_t)node * 32 + c0] = o;
}

extern "C" void kernel_launch(void* const* d_in, const int* in_sizes, int n_in,
                              void* d_out, int out_size, void* d_ws, size_t ws_size,
                              hipStream_t stream) {
    const float* x    = (const float*)d_in[0];
    const int* ei     = (const int*)d_in[1];
    const float* eatt = (const float*)d_in[2];
    const float* Wl1 = (const float*)d_in[3],  *bl1 = (const float*)d_in[4];
    const float* Wr1 = (const float*)d_in[5],  *br1 = (const float*)d_in[6];
    const float* We1 = (const float*)d_in[7],  *att1 = (const float*)d_in[8];
    const float* b1  = (const float*)d_in[9];
    const float* Wl2 = (const float*)d_in[10], *bl2 = (const float*)d_in[11];
    const float* Wr2 = (const float*)d_in[12], *br2 = (const float*)d_in[13];
    const float* We2 = (const float*)d_in[14], *att2 = (const float*)d_in[15];
    const float* b2  = (const float*)d_in[16], *Rw2 = (const float*)d_in[17];
    const float* Wl3 = (const float*)d_in[18], *bl3 = (const float*)d_in[19];
    const float* Wr3 = (const float*)d_in[20], *br3 = (const float*)d_in[21];
    const float* We3 = (const float*)d_in[22], *att3 = (const float*)d_in[23];
    const float* b3  = (const float*)d_in[24];

    const int* srcp = ei;
    const int* dstp = ei + EE;

    // ---- workspace layout (~84 MB) ----
    char* w = (char*)d_ws;
    size_t off = 0;
    auto alloc = [&](size_t bytes) { char* p = w + off; off += (bytes + 255) & ~size_t(255); return p; };
    int*    rowcnt   = (int*)alloc((size_t)NN * 4);
    int*    rowptr   = (int*)alloc((size_t)(NN + 1) * 4);
    int*    cursor   = (int*)alloc((size_t)NN * 4);
    int*    blocksum = (int*)alloc(256 * 4);
    int*    local    = (int*)alloc((size_t)NN * 4);
    ERec*   csr      = (ERec*)alloc((size_t)(EE + NN) * sizeof(ERec));
    __half* xlbuf    = (__half*)alloc((size_t)NN * 128 * 2);
    __half* xrbuf    = (__half*)alloc((size_t)NN * 128 * 2);
    float*  hA       = (float*)alloc((size_t)NN * 32 * 4);
    float*  hB       = (float*)alloc((size_t)NN * 128 * 4);

    int nb = cdiv(NN, 256);

    // ---- CSR build (self-loop in front slot of each row) ----
    hipMemsetAsync(rowcnt, 0, (size_t)NN * 4, stream);
    hist_kernel<<<cdiv(EE, 256), 256, 0, stream>>>(dstp, rowcnt, EE);
    scan1_kernel<<<nb, 256, 0, stream>>>(rowcnt, local, blocksum, NN);
    scan2_kernel<<<1, 256, 0, stream>>>(blocksum, nb);
    scan3_kernel<<<nb, 256, 0, stream>>>(local, blocksum, rowcnt, rowptr, cursor, csr, NN);
    scatter_kernel<<<cdiv(EE, 256), 256, 0, stream>>>(
        srcp, dstp, eatt, cursor, csr, EE);
    loop_sea_kernel<<<cdiv(NN, 4), 256, 0, stream>>>(rowptr, csr, NN);

    // ---- layer 1: IN=16 -> H=4, C=8 (CT=32) ----
    node_linear_kernel<16, 32><<<cdiv(NN, 8), dim3(32, 8), 0, stream>>>(
        x, Wl1, bl1, Wr1, br1, xlbuf, xrbuf, NN);
    agg32_kernel<8, true><<<cdiv(NN, 16), 256, 0, stream>>>(
        rowptr, csr, xlbuf, xrbuf, We1, att1, b1, hA, NN);

    // ---- layer 2: IN=32 -> H=4, C=32 (CT=128), residual ----
    node_linear_kernel<32, 128><<<cdiv(NN, 2), dim3(128, 2), 0, stream>>>(
        hA, Wl2, bl2, Wr2, br2, xlbuf, xrbuf, NN);
    agg128_kernel<true, true><<<cdiv(NN, 4), 256, 0, stream>>>(
        rowptr, csr, xlbuf, xrbuf, We2, att2, b2, hA, Rw2, hB, NN);

    // ---- layer 3: IN=128 -> H=1, C=32 (CT=32) ----
    node_linear_kernel<128, 32><<<cdiv(NN, 8), dim3(32, 8), 0, stream>>>(
        hB, Wl3, bl3, Wr3, br3, xlbuf, xrbuf, NN);
    agg32_kernel<32, false><<<cdiv(NN, 16), 256, 0, stream>>>(
        rowptr, csr, xlbuf, xrbuf, We3, att3, b3,
        (float*)d_out, NN);
}

// Round 12
// 469.165 us; speedup vs baseline: 1.1278x; 1.0771x over previous
//
#include <hip/hip_runtime.h>
#include <hip/hip_fp16.h>

#define NEG_SLOPE 0.2f

constexpr int NN = 50000;   // nodes
constexpr int EE = 800000;  // edges (before self loops)

static inline int cdiv(int a, int b) { return (a + b - 1) / b; }

typedef _Float16 h2 __attribute__((ext_vector_type(2)));

#if __has_builtin(__builtin_amdgcn_fdot2)
static __device__ inline float fdot2f(h2 a, h2 b, float c) {
    return __builtin_amdgcn_fdot2(a, b, c, false);
}
#else
static __device__ inline float fdot2f(h2 a, h2 b, float c) {
    return c + (float)a.x * (float)b.x + (float)a.y * (float)b.y;
}
#endif

static __device__ inline h2 bch2(unsigned u) { return __builtin_bit_cast(h2, u); }

// 32-byte edge record: fp16 edge attrs + src id (always within one 64B line)
struct __align__(16) ERec {
    __half ea[8];   // 16 B
    int src;        // 4 B
    int pad[3];     // 12 B
};

// ================= CSR build =================
__global__ void hist_kernel(const int* __restrict__ dst, int* __restrict__ rowcnt, int E) {
    int t = blockIdx.x * blockDim.x + threadIdx.x;
    if (t < E) atomicAdd(&rowcnt[dst[t]], 1);
}

// block sums of (cnt+1)
__global__ void scana_kernel(const int* __restrict__ cnt, int* __restrict__ blocksum, int n) {
    __shared__ int s[256];
    int t = threadIdx.x, g = blockIdx.x * 256 + t;
    s[t] = (g < n) ? cnt[g] + 1 : 0;
    __syncthreads();
    for (int off = 128; off > 0; off >>= 1) {
        if (t < off) s[t] += s[t + off];
        __syncthreads();
    }
    if (t == 0) blocksum[blockIdx.x] = s[0];
}

// per-block: scan blocksums (<=256) in LDS + local scan -> rowptr/cursor/self-loop src
__global__ void scanb_kernel(const int* __restrict__ cnt, const int* __restrict__ blocksum,
                             int nbk, int* __restrict__ rowptr, int* __restrict__ cursor,
                             ERec* __restrict__ csr, int n) {
    __shared__ int bs[256];
    __shared__ int s[256];
    int t = threadIdx.x;
    bs[t] = (t < nbk) ? blocksum[t] : 0;
    __syncthreads();
    for (int off = 1; off < 256; off <<= 1) {
        int tv = (t >= off) ? bs[t - off] : 0; __syncthreads();
        bs[t] += tv; __syncthreads();
    }
    int blockoff = (blockIdx.x > 0) ? bs[blockIdx.x - 1] : 0;   // exclusive prefix
    int g = blockIdx.x * 256 + t;
    int val = (g < n) ? cnt[g] + 1 : 0;
    s[t] = val; __syncthreads();
    for (int off = 1; off < 256; off <<= 1) {
        int tv = (t >= off) ? s[t - off] : 0; __syncthreads();
        s[t] += tv; __syncthreads();
    }
    if (g >= n) return;
    int incl = s[t] + blockoff;
    rowptr[g + 1] = incl;
    int beg = incl - val;
    cursor[g] = beg + 1;          // slot `beg` reserved for the self loop
    csr[beg].src = g;             // self-loop source
    if (g == 0) rowptr[0] = 0;
}

// scatter edges into CSR records (fp16 edge attrs, CSR order; one 32B record)
__global__ void scatter_kernel(const int* __restrict__ src, const int* __restrict__ dst,
                               const float* __restrict__ eattr,
                               int* __restrict__ cursor, ERec* __restrict__ csr, int E) {
    int t = blockIdx.x * blockDim.x + threadIdx.x;
    if (t >= E) return;
    int d = dst[t];
    int pos = atomicAdd(&cursor[d], 1);
    const float4* ea4 = (const float4*)(eattr + (size_t)t * 8);
    float4 a = ea4[0], b = ea4[1];
    __half2 h0 = __floats2half2_rn(a.x, a.y);
    __half2 h1 = __floats2half2_rn(a.z, a.w);
    __half2 h2v = __floats2half2_rn(b.x, b.y);
    __half2 h3 = __floats2half2_rn(b.z, b.w);
    uint4 u;
    u.x = *(unsigned*)&h0; u.y = *(unsigned*)&h1;
    u.z = *(unsigned*)&h2v; u.w = *(unsigned*)&h3;
    ERec* r = &csr[pos];
    *(uint4*)r->ea = u;
    uint4 tail; tail.x = (unsigned)src[t]; tail.y = 0; tail.z = 0; tail.w = 0;
    *(uint4*)(&r->src) = tail;   // full 32 B record written
}

// fill each row's front slot with the mean of its (original) edge attrs
__global__ __launch_bounds__(256) void loop_sea_kernel(const int* __restrict__ rowptr,
                                                       ERec* __restrict__ csr, int n) {
    int wave = (blockIdx.x * 256 + threadIdx.x) >> 6;
    int lane = threadIdx.x & 63;
    if (wave >= n) return;
    int beg = rowptr[wave], end = rowptr[wave + 1];
    int k = lane & 7, j0 = lane >> 3;       // 8 edges in parallel
    float s = 0.f;
    for (int j = beg + 1 + j0; j < end; j += 8)
        s += __half2float(csr[j].ea[k]);
    s += __shfl_xor(s, 8); s += __shfl_xor(s, 16); s += __shfl_xor(s, 32);
    int cnt = end - beg - 1;
    if (lane < 8) csr[beg].ea[lane] = __float2half(s / fmaxf((float)cnt, 1.f));
}

// ======= node linear (fp32 input): xl = x@Wl+bl, xr = x@Wr+br (fp16 out) ======
template <int K, int CT>
__global__ __launch_bounds__(256) void node_linear_kernel(
    const float* __restrict__ x,
    const float* __restrict__ Wl, const float* __restrict__ bl,
    const float* __restrict__ Wr, const float* __restrict__ br,
    __half* __restrict__ xl, __half* __restrict__ xr, int n) {
    constexpr int NPB = 256 / CT;
    __shared__ float Wls[K * CT];
    __shared__ float Wrs[K * CT];
    __shared__ float xs[NPB * K];
    int tid = threadIdx.y * CT + threadIdx.x;
    for (int i = tid; i < K * CT; i += 256) { Wls[i] = Wl[i]; Wrs[i] = Wr[i]; }
    int node0 = blockIdx.x * NPB;
    for (int i = tid; i < NPB * K; i += 256) {
        int nd = node0 + i / K;
        xs[i] = (nd < n) ? x[(size_t)node0 * K + i] : 0.f;
    }
    __syncthreads();
    int node = node0 + threadIdx.y;
    if (node >= n) return;
    int c = threadIdx.x;
    float aL = bl[c], aR = br[c];
    const float* xrow = &xs[threadIdx.y * K];
    for (int k = 0; k < K; ++k) {
        float xv = xrow[k];
        aL = fmaf(xv, Wls[k * CT + c], aL);
        aR = fmaf(xv, Wrs[k * CT + c], aR);
    }
    xl[(size_t)node * CT + c] = __float2half(aL);
    xr[(size_t)node * CT + c] = __float2half(aR);
}

// ======= node linear (fp16 input, fp16 LDS weights, fdot2 accumulate) =========
template <int K, int CT>
__global__ __launch_bounds__(256) void node_linear_h_kernel(
    const __half* __restrict__ x,
    const float* __restrict__ Wl, const float* __restrict__ bl,
    const float* __restrict__ Wr, const float* __restrict__ br,
    __half* __restrict__ xl, __half* __restrict__ xr, int n) {
    constexpr int NPB = 256 / CT;
    constexpr int K2 = K / 2;
    __shared__ h2 Wls[K2 * CT];
    __shared__ h2 Wrs[K2 * CT];
    __shared__ h2 xs[NPB * K2];
    int tid = threadIdx.y * CT + threadIdx.x;
    for (int i = tid; i < K2 * CT; i += 256) {
        int k2 = i / CT, c = i % CT;
        Wls[i] = h2{(_Float16)Wl[(2 * k2) * CT + c], (_Float16)Wl[(2 * k2 + 1) * CT + c]};
        Wrs[i] = h2{(_Float16)Wr[(2 * k2) * CT + c], (_Float16)Wr[(2 * k2 + 1) * CT + c]};
    }
    int node0 = blockIdx.x * NPB;
    const unsigned* xg = (const unsigned*)(x + (size_t)node0 * K);
    for (int i = tid; i < NPB * K2; i += 256) {
        int nd = node0 + i / K2;
        unsigned u = (nd < n) ? xg[i] : 0u;
        xs[i] = bch2(u);
    }
    __syncthreads();
    int node = node0 + threadIdx.y;
    if (node >= n) return;
    int c = threadIdx.x;
    float aL = bl[c], aR = br[c];
    const h2* xrow = &xs[threadIdx.y * K2];
    for (int k = 0; k < K2; ++k) {
        h2 xv = xrow[k];
        aL = fdot2f(xv, Wls[k * CT + c], aL);
        aR = fdot2f(xv, Wrs[k * CT + c], aR);
    }
    xl[(size_t)node * CT + c] = __float2half(aL);
    xr[(size_t)node * CT + c] = __float2half(aR);
}

// ================= CSR aggregation, CT=128 (layer 2) =================
// One wave per node; 2 edge-chains per wave (32 lanes each, 4 ch/lane);
// one-deep software pipeline on record + xl gathers.  [round-5/9 validated]
// fp16 hres input, fp16 out.
template <bool RELU, bool RES>
__global__ __launch_bounds__(256) void agg128_kernel(
    const int* __restrict__ rowptr, const ERec* __restrict__ csr,
    const __half* __restrict__ xl, const __half* __restrict__ xr,
    const float* __restrict__ We,   // [8,128]
    const float* __restrict__ att,  // flat [128]
    const float* __restrict__ bias, // [128]
    const __half* __restrict__ hres, // [N,32] if RES
    const float* __restrict__ Rw,   // [32,128] if RES
    __half* __restrict__ out, int n) {
    __shared__ float Rws[RES ? 32 * 128 : 1];
    int tid = threadIdx.x;
    if (RES) {
        for (int i = tid; i < 32 * 128; i += 256) Rws[i] = Rw[i];
        __syncthreads();
    }
    int node = (blockIdx.x * 256 + tid) >> 6;
    int lane = tid & 63;
    if (node >= n) return;
    int sub = lane >> 5, cl = lane & 31;
    int c0 = 4 * cl;
    h2 wch[4][4];
    float attc[4];
#pragma unroll
    for (int c = 0; c < 4; ++c) {
        attc[c] = att[c0 + c];
#pragma unroll
        for (int k = 0; k < 4; ++k)
            wch[c][k] = h2{(_Float16)We[(2 * k) * 128 + c0 + c],
                           (_Float16)We[(2 * k + 1) * 128 + c0 + c]};
    }
    int beg = rowptr[node], end = rowptr[node + 1];
    uint2 xru = *(const uint2*)&xr[(size_t)node * 128 + c0];
    h2 xr01 = bch2(xru.x), xr23 = bch2(xru.y);
    float xrc[4] = {(float)xr01.x, (float)xr01.y, (float)xr23.x, (float)xr23.y};
    float num[4] = {0.f, 0.f, 0.f, 0.f};
    float den = 0.f;

    int j = beg + sub;
    uint4 uA, uB; int sA, sB; uint2 xA, xB;
    if (j < end) {
        uA = *(const uint4*)csr[j].ea; sA = csr[j].src;
        xA = *(const uint2*)&xl[(size_t)sA * 128 + c0];
    }
    if (j + 2 < end) {
        uB = *(const uint4*)csr[j + 2].ea; sB = csr[j + 2].src;
        xB = *(const uint2*)&xl[(size_t)sB * 128 + c0];
    }
    while (j < end) {
        int jf = j + 4;
        uint4 uC; int sC; uint2 xC;
        if (jf < end) {                        // prefetch 2 ahead
            uC = *(const uint4*)csr[jf].ea; sC = csr[jf].src;
            xC = *(const uint2*)&xl[(size_t)sC * 128 + c0];
        }
        h2 e0 = bch2(uA.x), e1 = bch2(uA.y), e2 = bch2(uA.z), e3 = bch2(uA.w);
        h2 xl01 = bch2(xA.x), xl23 = bch2(xA.y);
        float xls[4] = {(float)xl01.x, (float)xl01.y, (float)xl23.x, (float)xl23.y};
        float p = 0.f;
#pragma unroll
        for (int c = 0; c < 4; ++c) {
            float m = xls[c] + xrc[c];
            m = fdot2f(e0, wch[c][0], m); m = fdot2f(e1, wch[c][1], m);
            m = fdot2f(e2, wch[c][2], m); m = fdot2f(e3, wch[c][3], m);
            float sv = fmaxf(m, 0.f) + NEG_SLOPE * fminf(m, 0.f);
            p = fmaf(sv, attc[c], p);
        }
        p += __shfl_xor(p, 1); p += __shfl_xor(p, 2); p += __shfl_xor(p, 4); // 8-lane head
        float wgt = __expf(p);
#pragma unroll
        for (int c = 0; c < 4; ++c) num[c] = fmaf(wgt, xls[c], num[c]);
        den += wgt;
        j += 2;
        uA = uB; sA = sB; xA = xB;
        uB = uC; sB = sC; xB = xC;
    }
    // combine the two 32-lane chains
#pragma unroll
    for (int c = 0; c < 4; ++c) num[c] += __shfl_xor(num[c], 32);
    den += __shfl_xor(den, 32);
    if (sub == 0) {
        float inv = 1.f / den;
        float v[4];
#pragma unroll
        for (int c = 0; c < 4; ++c) v[c] = num[c] * inv + bias[c0 + c];
        if (RES) {
            float hr = __half2float(hres[(size_t)node * 32 + cl]);
#pragma unroll
            for (int k = 0; k < 32; ++k) {
                float hv = __shfl(hr, k, 32);
                float4 rw = *(const float4*)&Rws[k * 128 + c0];
                v[0] = fmaf(hv, rw.x, v[0]); v[1] = fmaf(hv, rw.y, v[1]);
                v[2] = fmaf(hv, rw.z, v[2]); v[3] = fmaf(hv, rw.w, v[3]);
            }
        }
        if (RELU) {
#pragma unroll
            for (int c = 0; c < 4; ++c) v[c] = fmaxf(v[c], 0.f);
        }
        __half2 o01 = __floats2half2_rn(v[0], v[1]);
        __half2 o23 = __floats2half2_rn(v[2], v[3]);
        uint2 ou; ou.x = *(unsigned*)&o01; ou.y = *(unsigned*)&o23;
        *(uint2*)&out[(size_t)node * 128 + c0] = ou;
    }
}

// ================= CSR aggregation, CT=32 (layers 1, 3) =================
// One 16-lane group per node; 2-slot pipeline; OUT = __half or float.
template <int HC, bool RELU, typename OUT>
__global__ __launch_bounds__(256) void agg32_kernel(
    const int* __restrict__ rowptr, const ERec* __restrict__ csr,
    const __half* __restrict__ xl, const __half* __restrict__ xr,
    const float* __restrict__ We,   // [8,32]
    const float* __restrict__ att,  // flat [32]
    const float* __restrict__ bias, // [32]
    OUT* __restrict__ out, int n) {
    int tid = threadIdx.x;
    int node = (blockIdx.x * 256 + tid) >> 4;   // one 16-lane group per node
    int q = tid & 15;
    if (node >= n) return;
    int c0 = 2 * q;
    h2 wc0[4], wc1[4];
#pragma unroll
    for (int k = 0; k < 4; ++k) {
        wc0[k] = h2{(_Float16)We[(2 * k) * 32 + c0], (_Float16)We[(2 * k + 1) * 32 + c0]};
        wc1[k] = h2{(_Float16)We[(2 * k) * 32 + c0 + 1], (_Float16)We[(2 * k + 1) * 32 + c0 + 1]};
    }
    float att0 = att[c0], att1 = att[c0 + 1];
    int beg = rowptr[node], end = rowptr[node + 1];
    h2 xrh = bch2(*(const unsigned*)&xr[(size_t)node * 32 + c0]);
    float xrc0 = (float)xrh.x, xrc1 = (float)xrh.y;
    float num0 = 0.f, num1 = 0.f, den = 0.f;

    int j = beg;
    uint4 uA, uB; int sA, sB; unsigned xA, xB;
    if (j < end) {
        uA = *(const uint4*)csr[j].ea; sA = csr[j].src;
        xA = *(const unsigned*)&xl[(size_t)sA * 32 + c0];
    }
    if (j + 1 < end) {
        uB = *(const uint4*)csr[j + 1].ea; sB = csr[j + 1].src;
        xB = *(const unsigned*)&xl[(size_t)sB * 32 + c0];
    }
    while (j < end) {
        int jf = j + 2;
        uint4 uC; int sC; unsigned xC;
        if (jf < end) {                        // prefetch 2 ahead
            uC = *(const uint4*)csr[jf].ea; sC = csr[jf].src;
            xC = *(const unsigned*)&xl[(size_t)sC * 32 + c0];
        }
        h2 e0 = bch2(uA.x), e1 = bch2(uA.y), e2 = bch2(uA.z), e3 = bch2(uA.w);
        h2 xlh = bch2(xA);
        float xls0 = (float)xlh.x, xls1 = (float)xlh.y;
        float m0 = xls0 + xrc0, m1 = xls1 + xrc1;
        m0 = fdot2f(e0, wc0[0], m0); m0 = fdot2f(e1, wc0[1], m0);
        m0 = fdot2f(e2, wc0[2], m0); m0 = fdot2f(e3, wc0[3], m0);
        m1 = fdot2f(e0, wc1[0], m1); m1 = fdot2f(e1, wc1[1], m1);
        m1 = fdot2f(e2, wc1[2], m1); m1 = fdot2f(e3, wc1[3], m1);
        float s0 = fmaxf(m0, 0.f) + NEG_SLOPE * fminf(m0, 0.f);
        float s1 = fmaxf(m1, 0.f) + NEG_SLOPE * fminf(m1, 0.f);
        float p = fmaf(s0, att0, s1 * att1);
#pragma unroll
        for (int off = HC / 4; off > 0; off >>= 1) p += __shfl_xor(p, off); // head group
        float wgt = __expf(p);
        num0 = fmaf(wgt, xls0, num0);
        num1 = fmaf(wgt, xls1, num1);
        den += wgt;
        j += 1;
        uA = uB; sA = sB; xA = xB;
        uB = uC; sB = sC; xB = xC;
    }
    float inv = 1.f / den;
    float v0 = num0 * inv + bias[c0];
    float v1 = num1 * inv + bias[c0 + 1];
    if (RELU) { v0 = fmaxf(v0, 0.f); v1 = fmaxf(v1, 0.f); }
    if constexpr (sizeof(OUT) == 2) {
        __half2 o = __floats2half2_rn(v0, v1);
        *(__half2*)&out[(size_t)node * 32 + c0] = o;
    } else {
        float2 o; o.x = v0; o.y = v1;
        *(float2*)&out[(size_t)node * 32 + c0] = o;
    }
}

extern "C" void kernel_launch(void* const* d_in, const int* in_sizes, int n_in,
                              void* d_out, int out_size, void* d_ws, size_t ws_size,
                              hipStream_t stream) {
    const float* x    = (const float*)d_in[0];
    const int* ei     = (const int*)d_in[1];
    const float* eatt = (const float*)d_in[2];
    const float* Wl1 = (const float*)d_in[3],  *bl1 = (const float*)d_in[4];
    const float* Wr1 = (const float*)d_in[5],  *br1 = (const float*)d_in[6];
    const float* We1 = (const float*)d_in[7],  *att1 = (const float*)d_in[8];
    const float* b1  = (const float*)d_in[9];
    const float* Wl2 = (const float*)d_in[10], *bl2 = (const float*)d_in[11];
    const float* Wr2 = (const float*)d_in[12], *br2 = (const float*)d_in[13];
    const float* We2 = (const float*)d_in[14], *att2 = (const float*)d_in[15];
    const float* b2  = (const float*)d_in[16], *Rw2 = (const float*)d_in[17];
    const float* Wl3 = (const float*)d_in[18], *bl3 = (const float*)d_in[19];
    const float* Wr3 = (const float*)d_in[20], *br3 = (const float*)d_in[21];
    const float* We3 = (const float*)d_in[22], *att3 = (const float*)d_in[23];
    const float* b3  = (const float*)d_in[24];

    const int* srcp = ei;
    const int* dstp = ei + EE;

    // ---- workspace layout (~70 MB) ----
    char* w = (char*)d_ws;
    size_t off = 0;
    auto alloc = [&](size_t bytes) { char* p = w + off; off += (bytes + 255) & ~size_t(255); return p; };
    int*    rowcnt   = (int*)alloc((size_t)NN * 4);
    int*    rowptr   = (int*)alloc((size_t)(NN + 1) * 4);
    int*    cursor   = (int*)alloc((size_t)NN * 4);
    int*    blocksum = (int*)alloc(256 * 4);
    ERec*   csr      = (ERec*)alloc((size_t)(EE + NN) * sizeof(ERec));
    __half* xlbuf    = (__half*)alloc((size_t)NN * 128 * 2);
    __half* xrbuf    = (__half*)alloc((size_t)NN * 128 * 2);
    __half* hA       = (__half*)alloc((size_t)NN * 32 * 2);
    __half* hB       = (__half*)alloc((size_t)NN * 128 * 2);

    int nb = cdiv(NN, 256);

    // ---- CSR build (self-loop in front slot of each row) ----
    hipMemsetAsync(rowcnt, 0, (size_t)NN * 4, stream);
    hist_kernel<<<cdiv(EE, 256), 256, 0, stream>>>(dstp, rowcnt, EE);
    scana_kernel<<<nb, 256, 0, stream>>>(rowcnt, blocksum, NN);
    scanb_kernel<<<nb, 256, 0, stream>>>(rowcnt, blocksum, nb, rowptr, cursor, csr, NN);
    scatter_kernel<<<cdiv(EE, 256), 256, 0, stream>>>(
        srcp, dstp, eatt, cursor, csr, EE);
    loop_sea_kernel<<<cdiv(NN, 4), 256, 0, stream>>>(rowptr, csr, NN);

    // ---- layer 1: IN=16 -> H=4, C=8 (CT=32) ----
    node_linear_kernel<16, 32><<<cdiv(NN, 8), dim3(32, 8), 0, stream>>>(
        x, Wl1, bl1, Wr1, br1, xlbuf, xrbuf, NN);
    agg32_kernel<8, true, __half><<<cdiv(NN, 16), 256, 0, stream>>>(
        rowptr, csr, xlbuf, xrbuf, We1, att1, b1, hA, NN);

    // ---- layer 2: IN=32 -> H=4, C=32 (CT=128), residual ----
    node_linear_h_kernel<32, 128><<<cdiv(NN, 2), dim3(128, 2), 0, stream>>>(
        hA, Wl2, bl2, Wr2, br2, xlbuf, xrbuf, NN);
    agg128_kernel<true, true><<<cdiv(NN, 4), 256, 0, stream>>>(
        rowptr, csr, xlbuf, xrbuf, We2, att2, b2, hA, Rw2, hB, NN);

    // ---- layer 3: IN=128 -> H=1, C=32 (CT=32) ----
    node_linear_h_kernel<128, 32><<<cdiv(NN, 8), dim3(32, 8), 0, stream>>>(
        hB, Wl3, bl3, Wr3, br3, xlbuf, xrbuf, NN);
    agg32_kernel<32, false, float><<<cdiv(NN, 16), 256, 0, stream>>>(
        rowptr, csr, xlbuf, xrbuf, We3, att3, b3,
        (float*)d_out, NN);
}

// Round 13
// 468.632 us; speedup vs baseline: 1.1291x; 1.0011x over previous
//
#include <hip/hip_runtime.h>
#include <hip/hip_fp16.h>

#define NEG_SLOPE 0.2f

constexpr int NN = 50000;   // nodes
constexpr int EE = 800000;  // edges (before self loops)

static inline int cdiv(int a, int b) { return (a + b - 1) / b; }

typedef _Float16 h2 __attribute__((ext_vector_type(2)));

#if __has_builtin(__builtin_amdgcn_fdot2)
static __device__ inline float fdot2f(h2 a, h2 b, float c) {
    return __builtin_amdgcn_fdot2(a, b, c, false);
}
#else
static __device__ inline float fdot2f(h2 a, h2 b, float c) {
    return c + (float)a.x * (float)b.x + (float)a.y * (float)b.y;
}
#endif

static __device__ inline h2 bch2(unsigned u) { return __builtin_bit_cast(h2, u); }

// 32-byte edge record: fp16 edge attrs + src id (always within one 64B line)
struct __align__(16) ERec {
    __half ea[8];   // 16 B
    int src;        // 4 B
    int pad[3];     // 12 B
};

// ================= CSR build =================
__global__ void hist_kernel(const int* __restrict__ dst, int* __restrict__ rowcnt, int E) {
    int t = blockIdx.x * blockDim.x + threadIdx.x;
    if (t < E) atomicAdd(&rowcnt[dst[t]], 1);
}

// block sums of (cnt+1)
__global__ void scana_kernel(const int* __restrict__ cnt, int* __restrict__ blocksum, int n) {
    __shared__ int s[256];
    int t = threadIdx.x, g = blockIdx.x * 256 + t;
    s[t] = (g < n) ? cnt[g] + 1 : 0;
    __syncthreads();
    for (int off = 128; off > 0; off >>= 1) {
        if (t < off) s[t] += s[t + off];
        __syncthreads();
    }
    if (t == 0) blocksum[blockIdx.x] = s[0];
}

// per-block: scan blocksums (<=256) in LDS + local scan -> rowptr/cursor/self-loop src
__global__ void scanb_kernel(const int* __restrict__ cnt, const int* __restrict__ blocksum,
                             int nbk, int* __restrict__ rowptr, int* __restrict__ cursor,
                             ERec* __restrict__ csr, int n) {
    __shared__ int bs[256];
    __shared__ int s[256];
    int t = threadIdx.x;
    bs[t] = (t < nbk) ? blocksum[t] : 0;
    __syncthreads();
    for (int off = 1; off < 256; off <<= 1) {
        int tv = (t >= off) ? bs[t - off] : 0; __syncthreads();
        bs[t] += tv; __syncthreads();
    }
    int blockoff = (blockIdx.x > 0) ? bs[blockIdx.x - 1] : 0;   // exclusive prefix
    int g = blockIdx.x * 256 + t;
    int val = (g < n) ? cnt[g] + 1 : 0;
    s[t] = val; __syncthreads();
    for (int off = 1; off < 256; off <<= 1) {
        int tv = (t >= off) ? s[t - off] : 0; __syncthreads();
        s[t] += tv; __syncthreads();
    }
    if (g >= n) return;
    int incl = s[t] + blockoff;
    rowptr[g + 1] = incl;
    int beg = incl - val;
    cursor[g] = beg + 1;          // slot `beg` reserved for the self loop
    csr[beg].src = g;             // self-loop source
    if (g == 0) rowptr[0] = 0;
}

// scatter edges into CSR records (fp16 edge attrs, CSR order; one 32B record)
__global__ void scatter_kernel(const int* __restrict__ src, const int* __restrict__ dst,
                               const float* __restrict__ eattr,
                               int* __restrict__ cursor, ERec* __restrict__ csr, int E) {
    int t = blockIdx.x * blockDim.x + threadIdx.x;
    if (t >= E) return;
    int d = dst[t];
    int pos = atomicAdd(&cursor[d], 1);
    const float4* ea4 = (const float4*)(eattr + (size_t)t * 8);
    float4 a = ea4[0], b = ea4[1];
    __half2 h0 = __floats2half2_rn(a.x, a.y);
    __half2 h1 = __floats2half2_rn(a.z, a.w);
    __half2 h2v = __floats2half2_rn(b.x, b.y);
    __half2 h3 = __floats2half2_rn(b.z, b.w);
    uint4 u;
    u.x = *(unsigned*)&h0; u.y = *(unsigned*)&h1;
    u.z = *(unsigned*)&h2v; u.w = *(unsigned*)&h3;
    ERec* r = &csr[pos];
    *(uint4*)r->ea = u;
    uint4 tail; tail.x = (unsigned)src[t]; tail.y = 0; tail.z = 0; tail.w = 0;
    *(uint4*)(&r->src) = tail;   // full 32 B record written
}

// ======= fused: node_linear layer-1 (blocks < NB1) + loop_sea (rest) =========
// nl1: K=16, CT=32, 8 nodes/block (flat-tid remap of the validated 2D kernel).
// loop_sea: fill each row's front slot with the mean of its edge attrs.
template <int NB1>
__global__ __launch_bounds__(256) void fused_nl1_loopsea_kernel(
    // nl1 args
    const float* __restrict__ x,
    const float* __restrict__ Wl, const float* __restrict__ bl,
    const float* __restrict__ Wr, const float* __restrict__ br,
    __half* __restrict__ xl, __half* __restrict__ xr,
    // loop_sea args
    const int* __restrict__ rowptr, ERec* __restrict__ csr, int n) {
    constexpr int K = 16, CT = 32, NPB = 8;
    __shared__ float Wls[K * CT];
    __shared__ float Wrs[K * CT];
    __shared__ float xs[NPB * K];
    int tid = threadIdx.x;
    if (blockIdx.x < NB1) {
        // ---- node_linear layer 1 ----
        int ty = tid >> 5, c = tid & 31;
        for (int i = tid; i < K * CT; i += 256) { Wls[i] = Wl[i]; Wrs[i] = Wr[i]; }
        int node0 = blockIdx.x * NPB;
        for (int i = tid; i < NPB * K; i += 256) {
            int nd = node0 + i / K;
            xs[i] = (nd < n) ? x[(size_t)node0 * K + i] : 0.f;
        }
        __syncthreads();
        int node = node0 + ty;
        if (node >= n) return;
        float aL = bl[c], aR = br[c];
        const float* xrow = &xs[ty * K];
        for (int k = 0; k < K; ++k) {
            float xv = xrow[k];
            aL = fmaf(xv, Wls[k * CT + c], aL);
            aR = fmaf(xv, Wrs[k * CT + c], aR);
        }
        xl[(size_t)node * CT + c] = __float2half(aL);
        xr[(size_t)node * CT + c] = __float2half(aR);
    } else {
        // ---- loop_sea ----
        int wave = ((blockIdx.x - NB1) * 256 + tid) >> 6;
        int lane = tid & 63;
        if (wave >= n) return;
        int beg = rowptr[wave], end = rowptr[wave + 1];
        int k = lane & 7, j0 = lane >> 3;       // 8 edges in parallel
        float s = 0.f;
        for (int j = beg + 1 + j0; j < end; j += 8)
            s += __half2float(csr[j].ea[k]);
        s += __shfl_xor(s, 8); s += __shfl_xor(s, 16); s += __shfl_xor(s, 32);
        int cnt = end - beg - 1;
        if (lane < 8) csr[beg].ea[lane] = __float2half(s / fmaxf((float)cnt, 1.f));
    }
}

// ======= node linear (fp16 input, fp16 LDS weights, fdot2 accumulate) =========
template <int K, int CT>
__global__ __launch_bounds__(256) void node_linear_h_kernel(
    const __half* __restrict__ x,
    const float* __restrict__ Wl, const float* __restrict__ bl,
    const float* __restrict__ Wr, const float* __restrict__ br,
    __half* __restrict__ xl, __half* __restrict__ xr, int n) {
    constexpr int NPB = 256 / CT;
    constexpr int K2 = K / 2;
    __shared__ h2 Wls[K2 * CT];
    __shared__ h2 Wrs[K2 * CT];
    __shared__ h2 xs[NPB * K2];
    int tid = threadIdx.y * CT + threadIdx.x;
    for (int i = tid; i < K2 * CT; i += 256) {
        int k2 = i / CT, c = i % CT;
        Wls[i] = h2{(_Float16)Wl[(2 * k2) * CT + c], (_Float16)Wl[(2 * k2 + 1) * CT + c]};
        Wrs[i] = h2{(_Float16)Wr[(2 * k2) * CT + c], (_Float16)Wr[(2 * k2 + 1) * CT + c]};
    }
    int node0 = blockIdx.x * NPB;
    const unsigned* xg = (const unsigned*)(x + (size_t)node0 * K);
    for (int i = tid; i < NPB * K2; i += 256) {
        int nd = node0 + i / K2;
        unsigned u = (nd < n) ? xg[i] : 0u;
        xs[i] = bch2(u);
    }
    __syncthreads();
    int node = node0 + threadIdx.y;
    if (node >= n) return;
    int c = threadIdx.x;
    float aL = bl[c], aR = br[c];
    const h2* xrow = &xs[threadIdx.y * K2];
    for (int k = 0; k < K2; ++k) {
        h2 xv = xrow[k];
        aL = fdot2f(xv, Wls[k * CT + c], aL);
        aR = fdot2f(xv, Wrs[k * CT + c], aR);
    }
    xl[(size_t)node * CT + c] = __float2half(aL);
    xr[(size_t)node * CT + c] = __float2half(aR);
}

// ================= CSR aggregation, CT=128 (layer 2) =================
// One wave per node; 2 edge-chains per wave (32 lanes each, 4 ch/lane);
// one-deep software pipeline on record + xl gathers.  [round-5/9 validated]
// fp16 hres input, fp16 out.
template <bool RELU, bool RES>
__global__ __launch_bounds__(256) void agg128_kernel(
    const int* __restrict__ rowptr, const ERec* __restrict__ csr,
    const __half* __restrict__ xl, const __half* __restrict__ xr,
    const float* __restrict__ We,   // [8,128]
    const float* __restrict__ att,  // flat [128]
    const float* __restrict__ bias, // [128]
    const __half* __restrict__ hres, // [N,32] if RES
    const float* __restrict__ Rw,   // [32,128] if RES
    __half* __restrict__ out, int n) {
    __shared__ float Rws[RES ? 32 * 128 : 1];
    int tid = threadIdx.x;
    if (RES) {
        for (int i = tid; i < 32 * 128; i += 256) Rws[i] = Rw[i];
        __syncthreads();
    }
    int node = (blockIdx.x * 256 + tid) >> 6;
    int lane = tid & 63;
    if (node >= n) return;
    int sub = lane >> 5, cl = lane & 31;
    int c0 = 4 * cl;
    h2 wch[4][4];
    float attc[4];
#pragma unroll
    for (int c = 0; c < 4; ++c) {
        attc[c] = att[c0 + c];
#pragma unroll
        for (int k = 0; k < 4; ++k)
            wch[c][k] = h2{(_Float16)We[(2 * k) * 128 + c0 + c],
                           (_Float16)We[(2 * k + 1) * 128 + c0 + c]};
    }
    int beg = rowptr[node], end = rowptr[node + 1];
    uint2 xru = *(const uint2*)&xr[(size_t)node * 128 + c0];
    h2 xr01 = bch2(xru.x), xr23 = bch2(xru.y);
    float xrc[4] = {(float)xr01.x, (float)xr01.y, (float)xr23.x, (float)xr23.y};
    float num[4] = {0.f, 0.f, 0.f, 0.f};
    float den = 0.f;

    int j = beg + sub;
    uint4 uA, uB; int sA, sB; uint2 xA, xB;
    if (j < end) {
        uA = *(const uint4*)csr[j].ea; sA = csr[j].src;
        xA = *(const uint2*)&xl[(size_t)sA * 128 + c0];
    }
    if (j + 2 < end) {
        uB = *(const uint4*)csr[j + 2].ea; sB = csr[j + 2].src;
        xB = *(const uint2*)&xl[(size_t)sB * 128 + c0];
    }
    while (j < end) {
        int jf = j + 4;
        uint4 uC; int sC; uint2 xC;
        if (jf < end) {                        // prefetch 2 ahead
            uC = *(const uint4*)csr[jf].ea; sC = csr[jf].src;
            xC = *(const uint2*)&xl[(size_t)sC * 128 + c0];
        }
        h2 e0 = bch2(uA.x), e1 = bch2(uA.y), e2 = bch2(uA.z), e3 = bch2(uA.w);
        h2 xl01 = bch2(xA.x), xl23 = bch2(xA.y);
        float xls[4] = {(float)xl01.x, (float)xl01.y, (float)xl23.x, (float)xl23.y};
        float p = 0.f;
#pragma unroll
        for (int c = 0; c < 4; ++c) {
            float m = xls[c] + xrc[c];
            m = fdot2f(e0, wch[c][0], m); m = fdot2f(e1, wch[c][1], m);
            m = fdot2f(e2, wch[c][2], m); m = fdot2f(e3, wch[c][3], m);
            float sv = fmaxf(m, 0.f) + NEG_SLOPE * fminf(m, 0.f);
            p = fmaf(sv, attc[c], p);
        }
        p += __shfl_xor(p, 1); p += __shfl_xor(p, 2); p += __shfl_xor(p, 4); // 8-lane head
        float wgt = __expf(p);
#pragma unroll
        for (int c = 0; c < 4; ++c) num[c] = fmaf(wgt, xls[c], num[c]);
        den += wgt;
        j += 2;
        uA = uB; sA = sB; xA = xB;
        uB = uC; sB = sC; xB = xC;
    }
    // combine the two 32-lane chains
#pragma unroll
    for (int c = 0; c < 4; ++c) num[c] += __shfl_xor(num[c], 32);
    den += __shfl_xor(den, 32);
    if (sub == 0) {
        float inv = 1.f / den;
        float v[4];
#pragma unroll
        for (int c = 0; c < 4; ++c) v[c] = num[c] * inv + bias[c0 + c];
        if (RES) {
            float hr = __half2float(hres[(size_t)node * 32 + cl]);
#pragma unroll
            for (int k = 0; k < 32; ++k) {
                float hv = __shfl(hr, k, 32);
                float4 rw = *(const float4*)&Rws[k * 128 + c0];
                v[0] = fmaf(hv, rw.x, v[0]); v[1] = fmaf(hv, rw.y, v[1]);
                v[2] = fmaf(hv, rw.z, v[2]); v[3] = fmaf(hv, rw.w, v[3]);
            }
        }
        if (RELU) {
#pragma unroll
            for (int c = 0; c < 4; ++c) v[c] = fmaxf(v[c], 0.f);
        }
        __half2 o01 = __floats2half2_rn(v[0], v[1]);
        __half2 o23 = __floats2half2_rn(v[2], v[3]);
        uint2 ou; ou.x = *(unsigned*)&o01; ou.y = *(unsigned*)&o23;
        *(uint2*)&out[(size_t)node * 128 + c0] = ou;
    }
}

// ================= CSR aggregation, CT=32 (layers 1, 3) =================
// One 16-lane group per node; 2-slot pipeline; OUT = __half or float.
template <int HC, bool RELU, typename OUT>
__global__ __launch_bounds__(256) void agg32_kernel(
    const int* __restrict__ rowptr, const ERec* __restrict__ csr,
    const __half* __restrict__ xl, const __half* __restrict__ xr,
    const float* __restrict__ We,   // [8,32]
    const float* __restrict__ att,  // flat [32]
    const float* __restrict__ bias, // [32]
    OUT* __restrict__ out, int n) {
    int tid = threadIdx.x;
    int node = (blockIdx.x * 256 + tid) >> 4;   // one 16-lane group per node
    int q = tid & 15;
    if (node >= n) return;
    int c0 = 2 * q;
    h2 wc0[4], wc1[4];
#pragma unroll
    for (int k = 0; k < 4; ++k) {
        wc0[k] = h2{(_Float16)We[(2 * k) * 32 + c0], (_Float16)We[(2 * k + 1) * 32 + c0]};
        wc1[k] = h2{(_Float16)We[(2 * k) * 32 + c0 + 1], (_Float16)We[(2 * k + 1) * 32 + c0 + 1]};
    }
    float att0 = att[c0], att1 = att[c0 + 1];
    int beg = rowptr[node], end = rowptr[node + 1];
    h2 xrh = bch2(*(const unsigned*)&xr[(size_t)node * 32 + c0]);
    float xrc0 = (float)xrh.x, xrc1 = (float)xrh.y;
    float num0 = 0.f, num1 = 0.f, den = 0.f;

    int j = beg;
    uint4 uA, uB; int sA, sB; unsigned xA, xB;
    if (j < end) {
        uA = *(const uint4*)csr[j].ea; sA = csr[j].src;
        xA = *(const unsigned*)&xl[(size_t)sA * 32 + c0];
    }
    if (j + 1 < end) {
        uB = *(const uint4*)csr[j + 1].ea; sB = csr[j + 1].src;
        xB = *(const unsigned*)&xl[(size_t)sB * 32 + c0];
    }
    while (j < end) {
        int jf = j + 2;
        uint4 uC; int sC; unsigned xC;
        if (jf < end) {                        // prefetch 2 ahead
            uC = *(const uint4*)csr[jf].ea; sC = csr[jf].src;
            xC = *(const unsigned*)&xl[(size_t)sC * 32 + c0];
        }
        h2 e0 = bch2(uA.x), e1 = bch2(uA.y), e2 = bch2(uA.z), e3 = bch2(uA.w);
        h2 xlh = bch2(xA);
        float xls0 = (float)xlh.x, xls1 = (float)xlh.y;
        float m0 = xls0 + xrc0, m1 = xls1 + xrc1;
        m0 = fdot2f(e0, wc0[0], m0); m0 = fdot2f(e1, wc0[1], m0);
        m0 = fdot2f(e2, wc0[2], m0); m0 = fdot2f(e3, wc0[3], m0);
        m1 = fdot2f(e0, wc1[0], m1); m1 = fdot2f(e1, wc1[1], m1);
        m1 = fdot2f(e2, wc1[2], m1); m1 = fdot2f(e3, wc1[3], m1);
        float s0 = fmaxf(m0, 0.f) + NEG_SLOPE * fminf(m0, 0.f);
        float s1 = fmaxf(m1, 0.f) + NEG_SLOPE * fminf(m1, 0.f);
        float p = fmaf(s0, att0, s1 * att1);
#pragma unroll
        for (int off = HC / 4; off > 0; off >>= 1) p += __shfl_xor(p, off); // head group
        float wgt = __expf(p);
        num0 = fmaf(wgt, xls0, num0);
        num1 = fmaf(wgt, xls1, num1);
        den += wgt;
        j += 1;
        uA = uB; sA = sB; xA = xB;
        uB = uC; sB = sC; xB = xC;
    }
    float inv = 1.f / den;
    float v0 = num0 * inv + bias[c0];
    float v1 = num1 * inv + bias[c0 + 1];
    if (RELU) { v0 = fmaxf(v0, 0.f); v1 = fmaxf(v1, 0.f); }
    if constexpr (sizeof(OUT) == 2) {
        __half2 o = __floats2half2_rn(v0, v1);
        *(__half2*)&out[(size_t)node * 32 + c0] = o;
    } else {
        float2 o; o.x = v0; o.y = v1;
        *(float2*)&out[(size_t)node * 32 + c0] = o;
    }
}

extern "C" void kernel_launch(void* const* d_in, const int* in_sizes, int n_in,
                              void* d_out, int out_size, void* d_ws, size_t ws_size,
                              hipStream_t stream) {
    const float* x    = (const float*)d_in[0];
    const int* ei     = (const int*)d_in[1];
    const float* eatt = (const float*)d_in[2];
    const float* Wl1 = (const float*)d_in[3],  *bl1 = (const float*)d_in[4];
    const float* Wr1 = (const float*)d_in[5],  *br1 = (const float*)d_in[6];
    const float* We1 = (const float*)d_in[7],  *att1 = (const float*)d_in[8];
    const float* b1  = (const float*)d_in[9];
    const float* Wl2 = (const float*)d_in[10], *bl2 = (const float*)d_in[11];
    const float* Wr2 = (const float*)d_in[12], *br2 = (const float*)d_in[13];
    const float* We2 = (const float*)d_in[14], *att2 = (const float*)d_in[15];
    const float* b2  = (const float*)d_in[16], *Rw2 = (const float*)d_in[17];
    const float* Wl3 = (const float*)d_in[18], *bl3 = (const float*)d_in[19];
    const float* Wr3 = (const float*)d_in[20], *br3 = (const float*)d_in[21];
    const float* We3 = (const float*)d_in[22], *att3 = (const float*)d_in[23];
    const float* b3  = (const float*)d_in[24];

    const int* srcp = ei;
    const int* dstp = ei + EE;

    // ---- workspace layout (~70 MB) ----
    char* w = (char*)d_ws;
    size_t off = 0;
    auto alloc = [&](size_t bytes) { char* p = w + off; off += (bytes + 255) & ~size_t(255); return p; };
    int*    rowcnt   = (int*)alloc((size_t)NN * 4);
    int*    rowptr   = (int*)alloc((size_t)(NN + 1) * 4);
    int*    cursor   = (int*)alloc((size_t)NN * 4);
    int*    blocksum = (int*)alloc(256 * 4);
    ERec*   csr      = (ERec*)alloc((size_t)(EE + NN) * sizeof(ERec));
    __half* xlbuf    = (__half*)alloc((size_t)NN * 128 * 2);
    __half* xrbuf    = (__half*)alloc((size_t)NN * 128 * 2);
    __half* hA       = (__half*)alloc((size_t)NN * 32 * 2);
    __half* hB       = (__half*)alloc((size_t)NN * 128 * 2);

    int nb = cdiv(NN, 256);

    // ---- CSR build (self-loop in front slot of each row) ----
    hipMemsetAsync(rowcnt, 0, (size_t)NN * 4, stream);
    hist_kernel<<<cdiv(EE, 256), 256, 0, stream>>>(dstp, rowcnt, EE);
    scana_kernel<<<nb, 256, 0, stream>>>(rowcnt, blocksum, NN);
    scanb_kernel<<<nb, 256, 0, stream>>>(rowcnt, blocksum, nb, rowptr, cursor, csr, NN);
    scatter_kernel<<<cdiv(EE, 256), 256, 0, stream>>>(
        srcp, dstp, eatt, cursor, csr, EE);

    // ---- fused: loop_sea + node_linear layer 1 (independent of each other) ----
    constexpr int NB1 = (NN + 7) / 8;           // 6250 nl1 blocks
    int nb_ls = cdiv(NN, 4);                    // 12500 loop_sea blocks
    fused_nl1_loopsea_kernel<NB1><<<NB1 + nb_ls, 256, 0, stream>>>(
        x, Wl1, bl1, Wr1, br1, xlbuf, xrbuf, rowptr, csr, NN);

    // ---- layer 1 aggregation: H=4, C=8 (CT=32) ----
    agg32_kernel<8, true, __half><<<cdiv(NN, 16), 256, 0, stream>>>(
        rowptr, csr, xlbuf, xrbuf, We1, att1, b1, hA, NN);

    // ---- layer 2: IN=32 -> H=4, C=32 (CT=128), residual ----
    node_linear_h_kernel<32, 128><<<cdiv(NN, 2), dim3(128, 2), 0, stream>>>(
        hA, Wl2, bl2, Wr2, br2, xlbuf, xrbuf, NN);
    agg128_kernel<true, true><<<cdiv(NN, 4), 256, 0, stream>>>(
        rowptr, csr, xlbuf, xrbuf, We2, att2, b2, hA, Rw2, hB, NN);

    // ---- layer 3: IN=128 -> H=1, C=32 (CT=32) ----
    node_linear_h_kernel<128, 32><<<cdiv(NN, 8), dim3(32, 8), 0, stream>>>(
        hB, Wl3, bl3, Wr3, br3, xlbuf, xrbuf, NN);
    agg32_kernel<32, false, float><<<cdiv(NN, 16), 256, 0, stream>>>(
        rowptr, csr, xlbuf, xrbuf, We3, att3, b3,
        (float*)d_out, NN);
}

// Round 14
// 467.368 us; speedup vs baseline: 1.1322x; 1.0027x over previous
//
#include <hip/hip_runtime.h>
#include <hip/hip_fp16.h>

#define NEG_SLOPE 0.2f

constexpr int NN = 50000;   // nodes
constexpr int EE = 800000;  // edges (before self loops)

static inline int cdiv(int a, int b) { return (a + b - 1) / b; }

typedef _Float16 h2 __attribute__((ext_vector_type(2)));

#if __has_builtin(__builtin_amdgcn_fdot2)
static __device__ inline float fdot2f(h2 a, h2 b, float c) {
    return __builtin_amdgcn_fdot2(a, b, c, false);
}
#else
static __device__ inline float fdot2f(h2 a, h2 b, float c) {
    return c + (float)a.x * (float)b.x + (float)a.y * (float)b.y;
}
#endif

static __device__ inline h2 bch2(unsigned u) { return __builtin_bit_cast(h2, u); }

// 32-byte edge record: fp16 edge attrs + src id (always within one 64B line)
struct __align__(16) ERec {
    __half ea[8];   // 16 B
    int src;        // 4 B
    int pad[3];     // 12 B
};

// ================= CSR build =================
// int4-vectorized: 4 edges per thread
__global__ void hist_kernel(const int4* __restrict__ dst4, int* __restrict__ rowcnt, int E4) {
    int t = blockIdx.x * blockDim.x + threadIdx.x;
    if (t >= E4) return;
    int4 d = dst4[t];
    atomicAdd(&rowcnt[d.x], 1);
    atomicAdd(&rowcnt[d.y], 1);
    atomicAdd(&rowcnt[d.z], 1);
    atomicAdd(&rowcnt[d.w], 1);
}

// block sums of (cnt+1)
__global__ void scana_kernel(const int* __restrict__ cnt, int* __restrict__ blocksum, int n) {
    __shared__ int s[256];
    int t = threadIdx.x, g = blockIdx.x * 256 + t;
    s[t] = (g < n) ? cnt[g] + 1 : 0;
    __syncthreads();
    for (int off = 128; off > 0; off >>= 1) {
        if (t < off) s[t] += s[t + off];
        __syncthreads();
    }
    if (t == 0) blocksum[blockIdx.x] = s[0];
}

// per-block: scan blocksums (<=256) in LDS + local scan -> rowptr/cursor/self-loop src
__global__ void scanb_kernel(const int* __restrict__ cnt, const int* __restrict__ blocksum,
                             int nbk, int* __restrict__ rowptr, int* __restrict__ cursor,
                             ERec* __restrict__ csr, int n) {
    __shared__ int bs[256];
    __shared__ int s[256];
    int t = threadIdx.x;
    bs[t] = (t < nbk) ? blocksum[t] : 0;
    __syncthreads();
    for (int off = 1; off < 256; off <<= 1) {
        int tv = (t >= off) ? bs[t - off] : 0; __syncthreads();
        bs[t] += tv; __syncthreads();
    }
    int blockoff = (blockIdx.x > 0) ? bs[blockIdx.x - 1] : 0;   // exclusive prefix
    int g = blockIdx.x * 256 + t;
    int val = (g < n) ? cnt[g] + 1 : 0;
    s[t] = val; __syncthreads();
    for (int off = 1; off < 256; off <<= 1) {
        int tv = (t >= off) ? s[t - off] : 0; __syncthreads();
        s[t] += tv; __syncthreads();
    }
    if (g >= n) return;
    int incl = s[t] + blockoff;
    rowptr[g + 1] = incl;
    int beg = incl - val;
    cursor[g] = beg + 1;          // slot `beg` reserved for the self loop
    csr[beg].src = g;             // self-loop source
    if (g == 0) rowptr[0] = 0;
}

// scatter edges into CSR records (fp16 edge attrs, CSR order)
__global__ void scatter_kernel(const int* __restrict__ src, const int* __restrict__ dst,
                               const float* __restrict__ eattr,
                               int* __restrict__ cursor, ERec* __restrict__ csr, int E) {
    int t = blockIdx.x * blockDim.x + threadIdx.x;
    if (t >= E) return;
    int d = dst[t];
    int pos = atomicAdd(&cursor[d], 1);
    const float4* ea4 = (const float4*)(eattr + (size_t)t * 8);
    float4 a = ea4[0], b = ea4[1];
    __half2 h0 = __floats2half2_rn(a.x, a.y);
    __half2 h1 = __floats2half2_rn(a.z, a.w);
    __half2 h2v = __floats2half2_rn(b.x, b.y);
    __half2 h3 = __floats2half2_rn(b.z, b.w);
    uint4 u;
    u.x = *(unsigned*)&h0; u.y = *(unsigned*)&h1;
    u.z = *(unsigned*)&h2v; u.w = *(unsigned*)&h3;
    ERec* r = &csr[pos];
    *(uint4*)r->ea = u;
    r->src = src[t];              // 4B store (pad bytes never read)
}

// ======= fused: node_linear layer-1 (blocks < NB1) + loop_sea (rest) =========
template <int NB1>
__global__ __launch_bounds__(256) void fused_nl1_loopsea_kernel(
    const float* __restrict__ x,
    const float* __restrict__ Wl, const float* __restrict__ bl,
    const float* __restrict__ Wr, const float* __restrict__ br,
    __half* __restrict__ xl, __half* __restrict__ xr,
    const int* __restrict__ rowptr, ERec* __restrict__ csr, int n) {
    constexpr int K = 16, CT = 32, NPB = 8;
    __shared__ float Wls[K * CT];
    __shared__ float Wrs[K * CT];
    __shared__ float xs[NPB * K];
    int tid = threadIdx.x;
    if (blockIdx.x < NB1) {
        // ---- node_linear layer 1 ----
        int ty = tid >> 5, c = tid & 31;
        for (int i = tid; i < K * CT; i += 256) { Wls[i] = Wl[i]; Wrs[i] = Wr[i]; }
        int node0 = blockIdx.x * NPB;
        for (int i = tid; i < NPB * K; i += 256) {
            int nd = node0 + i / K;
            xs[i] = (nd < n) ? x[(size_t)node0 * K + i] : 0.f;
        }
        __syncthreads();
        int node = node0 + ty;
        if (node >= n) return;
        float aL = bl[c], aR = br[c];
        const float* xrow = &xs[ty * K];
        for (int k = 0; k < K; ++k) {
            float xv = xrow[k];
            aL = fmaf(xv, Wls[k * CT + c], aL);
            aR = fmaf(xv, Wrs[k * CT + c], aR);
        }
        xl[(size_t)node * CT + c] = __float2half(aL);
        xr[(size_t)node * CT + c] = __float2half(aR);
    } else {
        // ---- loop_sea ----
        int wave = ((blockIdx.x - NB1) * 256 + tid) >> 6;
        int lane = tid & 63;
        if (wave >= n) return;
        int beg = rowptr[wave], end = rowptr[wave + 1];
        int k = lane & 7, j0 = lane >> 3;       // 8 edges in parallel
        float s = 0.f;
        for (int j = beg + 1 + j0; j < end; j += 8)
            s += __half2float(csr[j].ea[k]);
        s += __shfl_xor(s, 8); s += __shfl_xor(s, 16); s += __shfl_xor(s, 32);
        int cnt = end - beg - 1;
        if (lane < 8) csr[beg].ea[lane] = __float2half(s / fmaxf((float)cnt, 1.f));
    }
}

// ======= node linear (fp16 input, fp16 LDS weights, fdot2 accumulate) =========
template <int K, int CT>
__global__ __launch_bounds__(256) void node_linear_h_kernel(
    const __half* __restrict__ x,
    const float* __restrict__ Wl, const float* __restrict__ bl,
    const float* __restrict__ Wr, const float* __restrict__ br,
    __half* __restrict__ xl, __half* __restrict__ xr, int n) {
    constexpr int NPB = 256 / CT;
    constexpr int K2 = K / 2;
    __shared__ h2 Wls[K2 * CT];
    __shared__ h2 Wrs[K2 * CT];
    __shared__ h2 xs[NPB * K2];
    int tid = threadIdx.y * CT + threadIdx.x;
    for (int i = tid; i < K2 * CT; i += 256) {
        int k2 = i / CT, c = i % CT;
        Wls[i] = h2{(_Float16)Wl[(2 * k2) * CT + c], (_Float16)Wl[(2 * k2 + 1) * CT + c]};
        Wrs[i] = h2{(_Float16)Wr[(2 * k2) * CT + c], (_Float16)Wr[(2 * k2 + 1) * CT + c]};
    }
    int node0 = blockIdx.x * NPB;
    const unsigned* xg = (const unsigned*)(x + (size_t)node0 * K);
    for (int i = tid; i < NPB * K2; i += 256) {
        int nd = node0 + i / K2;
        unsigned u = (nd < n) ? xg[i] : 0u;
        xs[i] = bch2(u);
    }
    __syncthreads();
    int node = node0 + threadIdx.y;
    if (node >= n) return;
    int c = threadIdx.x;
    float aL = bl[c], aR = br[c];
    const h2* xrow = &xs[threadIdx.y * K2];
    for (int k = 0; k < K2; ++k) {
        h2 xv = xrow[k];
        aL = fdot2f(xv, Wls[k * CT + c], aL);
        aR = fdot2f(xv, Wrs[k * CT + c], aR);
    }
    xl[(size_t)node * CT + c] = __float2half(aL);
    xr[(size_t)node * CT + c] = __float2half(aR);
}

// ================= CSR aggregation, CT=128 (layer 2) =================
// One wave per node; 2 edge-chains per wave (32 lanes each, 4 ch/lane);
// one-deep software pipeline on record + xl gathers.  [validated 105us optimum]
template <bool RELU, bool RES>
__global__ __launch_bounds__(256) void agg128_kernel(
    const int* __restrict__ rowptr, const ERec* __restrict__ csr,
    const __half* __restrict__ xl, const __half* __restrict__ xr,
    const float* __restrict__ We,   // [8,128]
    const float* __restrict__ att,  // flat [128]
    const float* __restrict__ bias, // [128]
    const __half* __restrict__ hres, // [N,32] if RES
    const float* __restrict__ Rw,   // [32,128] if RES
    __half* __restrict__ out, int n) {
    __shared__ float Rws[RES ? 32 * 128 : 1];
    int tid = threadIdx.x;
    if (RES) {
        for (int i = tid; i < 32 * 128; i += 256) Rws[i] = Rw[i];
        __syncthreads();
    }
    int node = (blockIdx.x * 256 + tid) >> 6;
    int lane = tid & 63;
    if (node >= n) return;
    int sub = lane >> 5, cl = lane & 31;
    int c0 = 4 * cl;
    h2 wch[4][4];
    float attc[4];
#pragma unroll
    for (int c = 0; c < 4; ++c) {
        attc[c] = att[c0 + c];
#pragma unroll
        for (int k = 0; k < 4; ++k)
            wch[c][k] = h2{(_Float16)We[(2 * k) * 128 + c0 + c],
                           (_Float16)We[(2 * k + 1) * 128 + c0 + c]};
    }
    int beg = rowptr[node], end = rowptr[node + 1];
    uint2 xru = *(const uint2*)&xr[(size_t)node * 128 + c0];
    h2 xr01 = bch2(xru.x), xr23 = bch2(xru.y);
    float xrc[4] = {(float)xr01.x, (float)xr01.y, (float)xr23.x, (float)xr23.y};
    float num[4] = {0.f, 0.f, 0.f, 0.f};
    float den = 0.f;

    int j = beg + sub;
    uint4 uA, uB; int sA, sB; uint2 xA, xB;
    if (j < end) {
        uA = *(const uint4*)csr[j].ea; sA = csr[j].src;
        xA = *(const uint2*)&xl[(size_t)sA * 128 + c0];
    }
    if (j + 2 < end) {
        uB = *(const uint4*)csr[j + 2].ea; sB = csr[j + 2].src;
        xB = *(const uint2*)&xl[(size_t)sB * 128 + c0];
    }
    while (j < end) {
        int jf = j + 4;
        uint4 uC; int sC; uint2 xC;
        if (jf < end) {                        // prefetch 2 ahead
            uC = *(const uint4*)csr[jf].ea; sC = csr[jf].src;
            xC = *(const uint2*)&xl[(size_t)sC * 128 + c0];
        }
        h2 e0 = bch2(uA.x), e1 = bch2(uA.y), e2 = bch2(uA.z), e3 = bch2(uA.w);
        h2 xl01 = bch2(xA.x), xl23 = bch2(xA.y);
        float xls[4] = {(float)xl01.x, (float)xl01.y, (float)xl23.x, (float)xl23.y};
        float p = 0.f;
#pragma unroll
        for (int c = 0; c < 4; ++c) {
            float m = xls[c] + xrc[c];
            m = fdot2f(e0, wch[c][0], m); m = fdot2f(e1, wch[c][1], m);
            m = fdot2f(e2, wch[c][2], m); m = fdot2f(e3, wch[c][3], m);
            float sv = fmaxf(m, 0.f) + NEG_SLOPE * fminf(m, 0.f);
            p = fmaf(sv, attc[c], p);
        }
        p += __shfl_xor(p, 1); p += __shfl_xor(p, 2); p += __shfl_xor(p, 4); // 8-lane head
        float wgt = __expf(p);
#pragma unroll
        for (int c = 0; c < 4; ++c) num[c] = fmaf(wgt, xls[c], num[c]);
        den += wgt;
        j += 2;
        uA = uB; sA = sB; xA = xB;
        uB = uC; sB = sC; xB = xC;
    }
    // combine the two 32-lane chains
#pragma unroll
    for (int c = 0; c < 4; ++c) num[c] += __shfl_xor(num[c], 32);
    den += __shfl_xor(den, 32);
    if (sub == 0) {
        float inv = 1.f / den;
        float v[4];
#pragma unroll
        for (int c = 0; c < 4; ++c) v[c] = num[c] * inv + bias[c0 + c];
        if (RES) {
            float hr = __half2float(hres[(size_t)node * 32 + cl]);
#pragma unroll
            for (int k = 0; k < 32; ++k) {
                float hv = __shfl(hr, k, 32);
                float4 rw = *(const float4*)&Rws[k * 128 + c0];
                v[0] = fmaf(hv, rw.x, v[0]); v[1] = fmaf(hv, rw.y, v[1]);
                v[2] = fmaf(hv, rw.z, v[2]); v[3] = fmaf(hv, rw.w, v[3]);
            }
        }
        if (RELU) {
#pragma unroll
            for (int c = 0; c < 4; ++c) v[c] = fmaxf(v[c], 0.f);
        }
        __half2 o01 = __floats2half2_rn(v[0], v[1]);
        __half2 o23 = __floats2half2_rn(v[2], v[3]);
        uint2 ou; ou.x = *(unsigned*)&o01; ou.y = *(unsigned*)&o23;
        *(uint2*)&out[(size_t)node * 128 + c0] = ou;
    }
}

// ================= CSR aggregation, CT=32 (layers 1, 3) =================
// One 16-lane group per node; 3-slot pipeline (spare VGPRs, no occupancy cliff);
// OUT = __half or float.
template <int HC, bool RELU, typename OUT>
__global__ __launch_bounds__(256) void agg32_kernel(
    const int* __restrict__ rowptr, const ERec* __restrict__ csr,
    const __half* __restrict__ xl, const __half* __restrict__ xr,
    const float* __restrict__ We,   // [8,32]
    const float* __restrict__ att,  // flat [32]
    const float* __restrict__ bias, // [32]
    OUT* __restrict__ out, int n) {
    int tid = threadIdx.x;
    int node = (blockIdx.x * 256 + tid) >> 4;   // one 16-lane group per node
    int q = tid & 15;
    if (node >= n) return;
    int c0 = 2 * q;
    h2 wc0[4], wc1[4];
#pragma unroll
    for (int k = 0; k < 4; ++k) {
        wc0[k] = h2{(_Float16)We[(2 * k) * 32 + c0], (_Float16)We[(2 * k + 1) * 32 + c0]};
        wc1[k] = h2{(_Float16)We[(2 * k) * 32 + c0 + 1], (_Float16)We[(2 * k + 1) * 32 + c0 + 1]};
    }
    float att0 = att[c0], att1 = att[c0 + 1];
    int beg = rowptr[node], end = rowptr[node + 1];
    h2 xrh = bch2(*(const unsigned*)&xr[(size_t)node * 32 + c0]);
    float xrc0 = (float)xrh.x, xrc1 = (float)xrh.y;
    float num0 = 0.f, num1 = 0.f, den = 0.f;

    int j = beg;
    uint4 uA, uB, uC; int sA, sB, sC; unsigned xA, xB, xC;
    if (j < end) {
        uA = *(const uint4*)csr[j].ea; sA = csr[j].src;
        xA = *(const unsigned*)&xl[(size_t)sA * 32 + c0];
    }
    if (j + 1 < end) {
        uB = *(const uint4*)csr[j + 1].ea; sB = csr[j + 1].src;
        xB = *(const unsigned*)&xl[(size_t)sB * 32 + c0];
    }
    if (j + 2 < end) {
        uC = *(const uint4*)csr[j + 2].ea; sC = csr[j + 2].src;
        xC = *(const unsigned*)&xl[(size_t)sC * 32 + c0];
    }
    while (j < end) {
        int jf = j + 3;
        uint4 uD; int sD; unsigned xD;
        if (jf < end) {                        // prefetch 3 ahead
            uD = *(const uint4*)csr[jf].ea; sD = csr[jf].src;
            xD = *(const unsigned*)&xl[(size_t)sD * 32 + c0];
        }
        h2 e0 = bch2(uA.x), e1 = bch2(uA.y), e2 = bch2(uA.z), e3 = bch2(uA.w);
        h2 xlh = bch2(xA);
        float xls0 = (float)xlh.x, xls1 = (float)xlh.y;
        float m0 = xls0 + xrc0, m1 = xls1 + xrc1;
        m0 = fdot2f(e0, wc0[0], m0); m0 = fdot2f(e1, wc0[1], m0);
        m0 = fdot2f(e2, wc0[2], m0); m0 = fdot2f(e3, wc0[3], m0);
        m1 = fdot2f(e0, wc1[0], m1); m1 = fdot2f(e1, wc1[1], m1);
        m1 = fdot2f(e2, wc1[2], m1); m1 = fdot2f(e3, wc1[3], m1);
        float s0 = fmaxf(m0, 0.f) + NEG_SLOPE * fminf(m0, 0.f);
        float s1 = fmaxf(m1, 0.f) + NEG_SLOPE * fminf(m1, 0.f);
        float p = fmaf(s0, att0, s1 * att1);
#pragma unroll
        for (int off = HC / 4; off > 0; off >>= 1) p += __shfl_xor(p, off); // head group
        float wgt = __expf(p);
        num0 = fmaf(wgt, xls0, num0);
        num1 = fmaf(wgt, xls1, num1);
        den += wgt;
        j += 1;
        uA = uB; sA = sB; xA = xB;
        uB = uC; sB = sC; xB = xC;
        uC = uD; sC = sD; xC = xD;
    }
    float inv = 1.f / den;
    float v0 = num0 * inv + bias[c0];
    float v1 = num1 * inv + bias[c0 + 1];
    if (RELU) { v0 = fmaxf(v0, 0.f); v1 = fmaxf(v1, 0.f); }
    if constexpr (sizeof(OUT) == 2) {
        __half2 o = __floats2half2_rn(v0, v1);
        *(__half2*)&out[(size_t)node * 32 + c0] = o;
    } else {
        float2 o; o.x = v0; o.y = v1;
        *(float2*)&out[(size_t)node * 32 + c0] = o;
    }
}

extern "C" void kernel_launch(void* const* d_in, const int* in_sizes, int n_in,
                              void* d_out, int out_size, void* d_ws, size_t ws_size,
                              hipStream_t stream) {
    const float* x    = (const float*)d_in[0];
    const int* ei     = (const int*)d_in[1];
    const float* eatt = (const float*)d_in[2];
    const float* Wl1 = (const float*)d_in[3],  *bl1 = (const float*)d_in[4];
    const float* Wr1 = (const float*)d_in[5],  *br1 = (const float*)d_in[6];
    const float* We1 = (const float*)d_in[7],  *att1 = (const float*)d_in[8];
    const float* b1  = (const float*)d_in[9];
    const float* Wl2 = (const float*)d_in[10], *bl2 = (const float*)d_in[11];
    const float* Wr2 = (const float*)d_in[12], *br2 = (const float*)d_in[13];
    const float* We2 = (const float*)d_in[14], *att2 = (const float*)d_in[15];
    const float* b2  = (const float*)d_in[16], *Rw2 = (const float*)d_in[17];
    const float* Wl3 = (const float*)d_in[18], *bl3 = (const float*)d_in[19];
    const float* Wr3 = (const float*)d_in[20], *br3 = (const float*)d_in[21];
    const float* We3 = (const float*)d_in[22], *att3 = (const float*)d_in[23];
    const float* b3  = (const float*)d_in[24];

    const int* srcp = ei;
    const int* dstp = ei + EE;

    // ---- workspace layout (~70 MB) ----
    char* w = (char*)d_ws;
    size_t off = 0;
    auto alloc = [&](size_t bytes) { char* p = w + off; off += (bytes + 255) & ~size_t(255); return p; };
    int*    rowcnt   = (int*)alloc((size_t)NN * 4);
    int*    rowptr   = (int*)alloc((size_t)(NN + 1) * 4);
    int*    cursor   = (int*)alloc((size_t)NN * 4);
    int*    blocksum = (int*)alloc(256 * 4);
    ERec*   csr      = (ERec*)alloc((size_t)(EE + NN) * sizeof(ERec));
    __half* xlbuf    = (__half*)alloc((size_t)NN * 128 * 2);
    __half* xrbuf    = (__half*)alloc((size_t)NN * 128 * 2);
    __half* hA       = (__half*)alloc((size_t)NN * 32 * 2);
    __half* hB       = (__half*)alloc((size_t)NN * 128 * 2);

    int nb = cdiv(NN, 256);

    // ---- CSR build (self-loop in front slot of each row) ----
    hipMemsetAsync(rowcnt, 0, (size_t)NN * 4, stream);
    hist_kernel<<<cdiv(EE / 4, 256), 256, 0, stream>>>((const int4*)dstp, rowcnt, EE / 4);
    scana_kernel<<<nb, 256, 0, stream>>>(rowcnt, blocksum, NN);
    scanb_kernel<<<nb, 256, 0, stream>>>(rowcnt, blocksum, nb, rowptr, cursor, csr, NN);
    scatter_kernel<<<cdiv(EE, 256), 256, 0, stream>>>(
        srcp, dstp, eatt, cursor, csr, EE);

    // ---- fused: loop_sea + node_linear layer 1 (independent of each other) ----
    constexpr int NB1 = (NN + 7) / 8;           // 6250 nl1 blocks
    int nb_ls = cdiv(NN, 4);                    // 12500 loop_sea blocks
    fused_nl1_loopsea_kernel<NB1><<<NB1 + nb_ls, 256, 0, stream>>>(
        x, Wl1, bl1, Wr1, br1, xlbuf, xrbuf, rowptr, csr, NN);

    // ---- layer 1 aggregation: H=4, C=8 (CT=32) ----
    agg32_kernel<8, true, __half><<<cdiv(NN, 16), 256, 0, stream>>>(
        rowptr, csr, xlbuf, xrbuf, We1, att1, b1, hA, NN);

    // ---- layer 2: IN=32 -> H=4, C=32 (CT=128), residual ----
    node_linear_h_kernel<32, 128><<<cdiv(NN, 2), dim3(128, 2), 0, stream>>>(
        hA, Wl2, bl2, Wr2, br2, xlbuf, xrbuf, NN);
    agg128_kernel<true, true><<<cdiv(NN, 4), 256, 0, stream>>>(
        rowptr, csr, xlbuf, xrbuf, We2, att2, b2, hA, Rw2, hB, NN);

    // ---- layer 3: IN=128 -> H=1, C=32 (CT=32) ----
    node_linear_h_kernel<128, 32><<<cdiv(NN, 8), dim3(32, 8), 0, stream>>>(
        hB, Wl3, bl3, Wr3, br3, xlbuf, xrbuf, NN);
    agg32_kernel<32, false, float><<<cdiv(NN, 16), 256, 0, stream>>>(
        rowptr, csr, xlbuf, xrbuf, We3, att3, b3,
        (float*)d_out, NN);
}